// Round 4
// baseline (1304.295 us; speedup 1.0000x reference)
//
#include <hip/hip_runtime.h>
#include <hip/hip_bf16.h>

#define N_NODES 400000
#define N_EDGES 1600000
#define N_GRAPHS 16384
#define CHUNK 32
#define NCHUNK (N_NODES / CHUNK)   // 12500

#define BSHIFT 11
#define BKT_N (1 << BSHIFT)                               // 2048 rows per bucket
#define NBKT ((N_NODES + BKT_N - 1) >> BSHIFT)            // 196 row-buckets
#define BIN_CHUNK 4096

typedef __attribute__((ext_vector_type(8))) short bf16x8;
typedef __attribute__((ext_vector_type(4))) float f32x4;
typedef unsigned short bfu;

__device__ __forceinline__ float rlane(float x, int k) {
    return __int_as_float(__builtin_amdgcn_readlane(__float_as_int(x), k));
}
__device__ __forceinline__ int rlanei(int x, int k) {
    return __builtin_amdgcn_readlane(x, k);
}

__device__ __forceinline__ short f2bf(float x) {  // RNE float -> bf16 bits
    unsigned u = __float_as_uint(x);
    unsigned r = (u + 0x7fffu + ((u >> 16) & 1u)) >> 16;
    return (short)r;
}
__device__ __forceinline__ float bf2f(short b) {
    return __uint_as_float(((unsigned)(unsigned short)b) << 16);
}
__device__ __forceinline__ float bfu2f(bfu b) {
    return __uint_as_float(((unsigned)b) << 16);
}

// ---- bucket counts: LDS histogram, ~196 global atomics per block ----
__global__ __launch_bounds__(256) void k_bcnt(const int* __restrict__ rows,
                                              int* __restrict__ bkt, int E) {
    __shared__ int l[NBKT];
    const int t = threadIdx.x;
    for (int i = t; i < NBKT; i += 256) l[i] = 0;
    __syncthreads();
    const int e0 = blockIdx.x * BIN_CHUNK;
#pragma unroll
    for (int k = 0; k < 16; ++k) {
        int e = e0 + k * 256 + t;
        if (e < E) atomicAdd(&l[rows[e] >> BSHIFT], 1);
    }
    __syncthreads();
    for (int i = t; i < NBKT; i += 256)
        if (l[i]) atomicAdd(&bkt[i], l[i]);
}

// ---- single-block exclusive scan over NBKT bucket counts ----
__global__ void k_bscan(const int* __restrict__ bkt, int* __restrict__ bbase,
                        int* __restrict__ bcur) {
    __shared__ int s[256];
    const int t = threadIdx.x;
    int v = (t < NBKT) ? bkt[t] : 0;
    s[t] = v; __syncthreads();
    for (int off = 1; off < 256; off <<= 1) {
        int x = (t >= off) ? s[t - off] : 0;
        __syncthreads();
        s[t] += x;
        __syncthreads();
    }
    int excl = s[t] - v;
    if (t < NBKT) { bbase[t] = excl; bcur[t] = excl; }
    if (t == NBKT) bbase[NBKT] = excl;   // = E
}

// ---- bin edges by row-bucket (LDS-combined reservations) ----
__global__ __launch_bounds__(256) void k_bin(const int* __restrict__ rows,
                                             const int* __restrict__ cols,
                                             int* __restrict__ bcur,
                                             int2* __restrict__ tmp, int E) {
    __shared__ int lcnt[NBKT];
    __shared__ int lbase[NBKT];
    const int t = threadIdx.x;
    const int e0 = blockIdx.x * BIN_CHUNK;
    for (int i = t; i < NBKT; i += 256) lcnt[i] = 0;
    __syncthreads();
    int r[16];
#pragma unroll
    for (int k = 0; k < 16; ++k) {
        int e = e0 + k * 256 + t;
        r[k] = (e < E) ? rows[e] : -1;
        if (r[k] >= 0) atomicAdd(&lcnt[r[k] >> BSHIFT], 1);
    }
    __syncthreads();
    for (int i = t; i < NBKT; i += 256) lbase[i] = atomicAdd(&bcur[i], lcnt[i]);
    __syncthreads();
    for (int i = t; i < NBKT; i += 256) lcnt[i] = 0;
    __syncthreads();
#pragma unroll
    for (int k = 0; k < 16; ++k) {
        int e = e0 + k * 256 + t;
        if (r[k] >= 0) {
            int b = r[k] >> BSHIFT;
            int p = lbase[b] + atomicAdd(&lcnt[b], 1);
            tmp[p] = make_int2(r[k], cols[e]);
        }
    }
}

// ---- per-bucket CSR build: row_ptr + dinv + cols scatter, all block-local ----
__global__ __launch_bounds__(256) void k_csr(const int2* __restrict__ tmp,
                                             const int* __restrict__ bbase,
                                             int* __restrict__ row_ptr,
                                             float* __restrict__ dinv,
                                             int* __restrict__ colsOut,
                                             int N, int E) {
    __shared__ int lcnt[BKT_N];
    __shared__ int lofs[BKT_N];
    __shared__ int tsum[256];
    const int t = threadIdx.x;
    const int b = blockIdx.x;
    const int r0 = b << BSHIFT;
    const int S = bbase[b];
    const int T = bbase[b + 1];
    for (int i = t; i < BKT_N; i += 256) lcnt[i] = 0;
    __syncthreads();
    for (int e = S + t; e < T; e += 256) atomicAdd(&lcnt[tmp[e].x - r0], 1);
    __syncthreads();
    // block scan of 2048 counts: 8 sequential per thread + 256-thread scan
    const int base8 = t * 8;
    int vals[8];
    int run = 0;
#pragma unroll
    for (int k = 0; k < 8; ++k) { vals[k] = run; run += lcnt[base8 + k]; }
    tsum[t] = run;
    __syncthreads();
    for (int off = 1; off < 256; off <<= 1) {
        int x = (t >= off) ? tsum[t - off] : 0;
        __syncthreads();
        tsum[t] += x;
        __syncthreads();
    }
    const int texcl = tsum[t] - run;
#pragma unroll
    for (int k = 0; k < 8; ++k) lofs[base8 + k] = texcl + vals[k];
    __syncthreads();
    for (int i = t; i < BKT_N; i += 256) {
        int node = r0 + i;
        if (node < N) {
            row_ptr[node] = S + lofs[i];
            dinv[node] = rsqrtf((float)lcnt[i] + 1.0f);
        }
    }
    if (b == 0 && t == 0) row_ptr[N] = E;
    __syncthreads();
    // scatter cols; lofs doubles as LDS cursor
    for (int e = S + t; e < T; e += 256) {
        int2 rc = tmp[e];
        int pos = S + atomicAdd(&lofs[rc.x - r0], 1);
        colsOut[pos] = rc.y;
    }
}

// ---- gstart from sorted batch via boundary detection (no atomics) ----
__global__ void k_gb(const int* __restrict__ batch, int* __restrict__ gstart,
                     int N, int G) {
    int i = blockIdx.x * blockDim.x + threadIdx.x;
    if (i <= N) {
        int b = (i < N) ? batch[i] : G;
        int prev = (i == 0) ? -1 : batch[i - 1];
        for (int g = prev + 1; g <= b; ++g) gstart[g] = i;
    }
}

// ---- MFMA GEMM (grid-stride over 16-node tiles).
// ABF16=0: A fp32, split hi/lo (3 MFMAs per nt,kt), optional dinv prescale.
// ABF16=1: A already bf16 (2 MFMAs per nt,kt). Output always bf16.
template <int IN_D, bool PRESCALE, bool ABF16>
__global__ __launch_bounds__(256, 4) void k_gemm_mfma(
        const void* __restrict__ in_, const float* __restrict__ W,
        const float* __restrict__ dinv, bfu* __restrict__ out, int nTiles) {
    constexpr int KT = IN_D / 32;
    const int lane = threadIdx.x & 63;
    const int m = lane & 15;
    const int q = lane >> 4;

    bf16x8 Bhi[4][KT], Blo[4][KT];
#pragma unroll
    for (int nt = 0; nt < 4; ++nt) {
#pragma unroll
        for (int kt = 0; kt < KT; ++kt) {
#pragma unroll
            for (int j = 0; j < 8; ++j) {
                int k = kt * 32 + q * 8 + j;
                float w = W[k * 64 + nt * 16 + m];
                short hi = f2bf(w);
                Bhi[nt][kt][j] = hi;
                Blo[nt][kt][j] = f2bf(w - bf2f(hi));
            }
        }
    }

    const int wv = (blockIdx.x * 256 + threadIdx.x) >> 6;
    const int nwv = (gridDim.x * 256) >> 6;

    for (int tile = wv; tile < nTiles; tile += nwv) {
        const int node0 = tile * 16;
        f32x4 C[4];
#pragma unroll
        for (int nt = 0; nt < 4; ++nt) C[nt] = (f32x4){0.f, 0.f, 0.f, 0.f};

        if (ABF16) {
            const bfu* rowb = (const bfu*)in_ + (size_t)(node0 + m) * IN_D + q * 8;
            bf16x8 A[KT];
#pragma unroll
            for (int kt = 0; kt < KT; ++kt) A[kt] = *(const bf16x8*)(rowb + kt * 32);
#pragma unroll
            for (int nt = 0; nt < 4; ++nt) {
#pragma unroll
                for (int kt = 0; kt < KT; ++kt) {
                    C[nt] = __builtin_amdgcn_mfma_f32_16x16x32_bf16(A[kt], Bhi[nt][kt], C[nt], 0, 0, 0);
                    C[nt] = __builtin_amdgcn_mfma_f32_16x16x32_bf16(A[kt], Blo[nt][kt], C[nt], 0, 0, 0);
                }
            }
        } else {
            const float dv = PRESCALE ? dinv[node0 + m] : 1.0f;
            const float* rowp = (const float*)in_ + (size_t)(node0 + m) * IN_D + q * 8;
            bf16x8 Ahi[KT], Alo[KT];
#pragma unroll
            for (int kt = 0; kt < KT; ++kt) {
                f32x4 a0 = *(const f32x4*)(rowp + kt * 32);
                f32x4 a1 = *(const f32x4*)(rowp + kt * 32 + 4);
#pragma unroll
                for (int j = 0; j < 4; ++j) {
                    float xx = PRESCALE ? dv * a0[j] : a0[j];
                    short hi = f2bf(xx);
                    Ahi[kt][j] = hi;
                    Alo[kt][j] = f2bf(xx - bf2f(hi));
                }
#pragma unroll
                for (int j = 0; j < 4; ++j) {
                    float xx = PRESCALE ? dv * a1[j] : a1[j];
                    short hi = f2bf(xx);
                    Ahi[kt][4 + j] = hi;
                    Alo[kt][4 + j] = f2bf(xx - bf2f(hi));
                }
            }
#pragma unroll
            for (int nt = 0; nt < 4; ++nt) {
#pragma unroll
                for (int kt = 0; kt < KT; ++kt) {
                    C[nt] = __builtin_amdgcn_mfma_f32_16x16x32_bf16(Ahi[kt], Bhi[nt][kt], C[nt], 0, 0, 0);
                    C[nt] = __builtin_amdgcn_mfma_f32_16x16x32_bf16(Ahi[kt], Blo[nt][kt], C[nt], 0, 0, 0);
                    C[nt] = __builtin_amdgcn_mfma_f32_16x16x32_bf16(Alo[kt], Bhi[nt][kt], C[nt], 0, 0, 0);
                }
            }
        }

        bfu* op = out + (size_t)node0 * 64;
#pragma unroll
        for (int nt = 0; nt < 4; ++nt) {
#pragma unroll
            for (int r = 0; r < 4; ++r) {
                op[(size_t)(q * 4 + r) * 64 + nt * 16 + m] = (bfu)f2bf(C[nt][r]);
            }
        }
    }
}

// ==== segmented-stream aggregation over bf16 M rows ====
// R4 = R1 structure (col window in VGPRs, per-edge readlane — NEVER a memory
// load per edge; R3 showed that serializes at ~4x cost) + dynamic chunk
// scheduling (lane-0 atomicAdd counter, 2048-block grid => occupancy pinned
// until drain) + 32-deep raw-ushort gather ring (loads stay unconverted until
// consumed one full unrolled block later -> stepped vmcnt waits).
// POOL=0: out[i] = bf16( dinv[i] * relu(dinv[i]*(M_i + sum_j M_j) + b) )
// POOL=1: h3 = relu(...) pooled per graph-run -> atomics into psum/pmax.
template <int POOL>
__global__ __launch_bounds__(256, 8) void k_agg_seg(
        const bfu* __restrict__ M, const float* __restrict__ bias,
        const int* __restrict__ row_ptr, const int* __restrict__ cols,
        const float* __restrict__ dinv, const int* __restrict__ batch,
        bfu* __restrict__ out, float* __restrict__ psum,
        float* __restrict__ pmax, int* __restrict__ ctr) {
    const int lane = threadIdx.x & 63;
    const float b = bias[lane];
    const bfu* Ml = M + lane;   // per-lane base; row r at Ml[r*64]

    for (;;) {
        int cw = 0;
        if (lane == 0) cw = atomicAdd(ctr, 1);
        const int c = __builtin_amdgcn_readfirstlane(cw);
        if (c >= NCHUNK) break;

        const int i0 = c * CHUNK;
        const int rpn = row_ptr[i0 + min(lane, CHUNK - 1) + 1];
        const int S = row_ptr[i0];
        const int ne = rlanei(rpn, CHUNK - 1) - S;
        const float dvv = dinv[i0 + min(lane, CHUNK - 1)];
        const int bvv = POOL ? batch[i0 + min(lane, CHUNK - 1)] : 0;

        int node = 0;
        int bnd = rlanei(rpn, 0) - S;
        float acc = 0.0f;
        float selfA = bfu2f(Ml[(size_t)i0 * 64]);
        float selfB = bfu2f(Ml[(size_t)(i0 + 1) * 64]);
        float selfC = bfu2f(Ml[(size_t)(i0 + 2) * 64]);
        int gcur = POOL ? rlanei(bvv, 0) : 0;
        float rsum = 0.0f, rmax = 0.0f;

        auto flush = [&]() {
            if (POOL) {
                atomicAdd(&psum[(size_t)gcur * 64 + lane], rsum);
                atomicMax((int*)&pmax[(size_t)gcur * 64 + lane], __float_as_int(rmax));
            }
        };
        auto finalize = [&]() {
            const float d = rlane(dvv, node);
            const float h = fmaxf(fmaf(d, selfA + acc, b), 0.0f);
            if (POOL) {
                const int g = rlanei(bvv, node);
                if (g != gcur) { flush(); gcur = g; rsum = 0.0f; rmax = 0.0f; }
                rsum += h;
                rmax = fmaxf(rmax, h);
            } else {
                out[(size_t)(i0 + node) * 64 + lane] = (bfu)f2bf(d * h);
            }
            acc = 0.0f;
            selfA = selfB;
            selfB = selfC;
            if (node + 3 < CHUNK) selfC = bfu2f(Ml[(size_t)(i0 + node + 3) * 64]);
            ++node;
            if (node < CHUNK) bnd = rlanei(rpn, node) - S;
        };

        if (ne > 0) {
            int bidx = 0;
            int a0 = S + lane, a1 = S + 64 + lane;
            int colv0 = (a0 < S + ne) ? cols[a0] : 0;
            int colv1 = (a1 < S + ne) ? cols[a1] : 0;
            unsigned ubuf[32];
#pragma unroll
            for (int k = 0; k < 32; ++k) {
                int e = min(k, ne - 1);
                int cc = rlanei(colv0, e);
                ubuf[k] = Ml[(size_t)cc * 64];
            }

            int j = 0;
            while (j + 32 <= ne) {
#pragma unroll
                for (int k = 0; k < 32; ++k) {
                    const int jj = j + k;
                    if ((jj & 63) == 0 && jj != 0) {
                        colv0 = colv1;
                        ++bidx;
                        int ad = S + (bidx + 1) * 64 + lane;
                        colv1 = (ad < S + ne) ? cols[ad] : 0;
                    }
                    while (jj == bnd) finalize();
                    acc += __uint_as_float(ubuf[k] << 16);
                    int ec = min(jj + 32, ne - 1);
                    int src = ((ec >> 6) == bidx) ? colv0 : colv1;
                    int cc = rlanei(src, ec & 63);
                    ubuf[k] = Ml[(size_t)cc * 64];
                }
                j += 32;
            }
            for (; j < ne; ++j) {
                while (j == bnd) finalize();
                acc += __uint_as_float(ubuf[j & 31] << 16);
            }
        }
        while (node < CHUNK) finalize();
        flush();
    }
}

// ---- assemble fused vector: [mean | max | relu(meta@Wm+bm) | emb | pad] ----
__global__ __launch_bounds__(256) void k_asm(
        const float* __restrict__ psum, const float* __restrict__ pmax,
        const int* __restrict__ gstart, const float* __restrict__ metadata,
        const int* __restrict__ species, const float* __restrict__ emb,
        const float* __restrict__ Wm, const float* __restrict__ bm,
        float* __restrict__ fused, int G) {
    const int lane = threadIdx.x & 63;
    int wv = (blockIdx.x * blockDim.x + threadIdx.x) >> 6;
    const int nw = (gridDim.x * blockDim.x) >> 6;
    const float bmr = bm[lane];
    float wmr[16];
#pragma unroll
    for (int k = 0; k < 16; ++k) wmr[k] = Wm[k * 64 + lane];
    for (int g = wv; g < G; g += nw) {
        float gc = (float)(gstart[g + 1] - gstart[g]);
        float mean = psum[(size_t)g * 64 + lane] / fmaxf(gc, 1.0f);
        float mx = pmax[(size_t)g * 64 + lane];
        float md = lane < 16 ? metadata[(size_t)g * 16 + lane] : 0.0f;
        float mval = bmr;
#pragma unroll
        for (int k = 0; k < 16; ++k) mval = fmaf(rlane(md, k), wmr[k], mval);
        mval = fmaxf(mval, 0.0f);
        const int sid = species[g];
        float* fr = fused + (size_t)g * 224;
        fr[lane] = mean;
        fr[64 + lane] = mx;
        fr[128 + lane] = mval;
        if (lane < 16) fr[192 + lane] = emb[(size_t)sid * 16 + lane];
        else if (lane < 32) fr[192 + lane] = 0.0f;
    }
}

// ---- MFMA predictor head ----
__global__ __launch_bounds__(256, 2) void k_pred_mfma(
        const float* __restrict__ fused, const float* __restrict__ Wp1,
        const float* __restrict__ bp1, const float* __restrict__ Wp2,
        const float* __restrict__ bp2, float* __restrict__ out, int G) {
    __shared__ __align__(16) short Whi[64 * 232];
    __shared__ __align__(16) short Wlo[64 * 232];
    const int t = threadIdx.x;
    for (int idx = t; idx < 64 * 232; idx += 256) {
        int n = idx / 232;
        int k = idx % 232;
        float w = (k < 208) ? Wp1[(size_t)k * 64 + n] : 0.0f;
        short hi = f2bf(w);
        Whi[n * 232 + k] = hi;
        Wlo[n * 232 + k] = f2bf(w - bf2f(hi));
    }
    __syncthreads();

    const int lane = t & 63;
    const int wave = t >> 6;
    const int m = lane & 15;
    const int q = lane >> 4;
    const int g0 = (blockIdx.x * 4 + wave) * 16;
    if (g0 >= G) return;

    const float* rowp = fused + (size_t)(g0 + m) * 224 + q * 8;

    f32x4 C[4];
#pragma unroll
    for (int nt = 0; nt < 4; ++nt) C[nt] = (f32x4){0.f, 0.f, 0.f, 0.f};

#pragma unroll
    for (int kt = 0; kt < 7; ++kt) {
        f32x4 a0 = *(const f32x4*)(rowp + kt * 32);
        f32x4 a1 = *(const f32x4*)(rowp + kt * 32 + 4);
        bf16x8 Ahi, Alo;
#pragma unroll
        for (int j = 0; j < 4; ++j) {
            short hi = f2bf(a0[j]);
            Ahi[j] = hi;
            Alo[j] = f2bf(a0[j] - bf2f(hi));
        }
#pragma unroll
        for (int j = 0; j < 4; ++j) {
            short hi = f2bf(a1[j]);
            Ahi[4 + j] = hi;
            Alo[4 + j] = f2bf(a1[j] - bf2f(hi));
        }
#pragma unroll
        for (int nt = 0; nt < 4; ++nt) {
            const int boff = (nt * 16 + m) * 232 + kt * 32 + q * 8;
            bf16x8 Bh = *(const bf16x8*)&Whi[boff];
            bf16x8 Bl = *(const bf16x8*)&Wlo[boff];
            C[nt] = __builtin_amdgcn_mfma_f32_16x16x32_bf16(Ahi, Bh, C[nt], 0, 0, 0);
            C[nt] = __builtin_amdgcn_mfma_f32_16x16x32_bf16(Ahi, Bl, C[nt], 0, 0, 0);
            C[nt] = __builtin_amdgcn_mfma_f32_16x16x32_bf16(Alo, Bh, C[nt], 0, 0, 0);
        }
    }

    float wp2r[4], bp1r[4];
#pragma unroll
    for (int nt = 0; nt < 4; ++nt) {
        wp2r[nt] = Wp2[nt * 16 + m];
        bp1r[nt] = bp1[nt * 16 + m];
    }
    const float bp2v = bp2[0];
    float s[4];
#pragma unroll
    for (int r = 0; r < 4; ++r) {
        float acc = 0.0f;
#pragma unroll
        for (int nt = 0; nt < 4; ++nt)
            acc += fmaxf(C[nt][r] + bp1r[nt], 0.0f) * wp2r[nt];
        s[r] = acc;
    }
#pragma unroll
    for (int off = 1; off < 16; off <<= 1) {
#pragma unroll
        for (int r = 0; r < 4; ++r) s[r] += __shfl_xor(s[r], off);
    }
    if (m == 0) {
#pragma unroll
        for (int r = 0; r < 4; ++r) out[g0 + q * 4 + r] = s[r] + bp2v;
    }
}

extern "C" void kernel_launch(void* const* d_in, const int* in_sizes, int n_in,
                              void* d_out, int out_size, void* d_ws, size_t ws_size,
                              hipStream_t stream) {
    const int N = N_NODES, E = N_EDGES, G = N_GRAPHS;

    const float* x        = (const float*)d_in[0];
    const float* metadata = (const float*)d_in[1];
    const int*   ei       = (const int*)d_in[2];
    const int*   batch    = (const int*)d_in[3];
    const int*   species  = (const int*)d_in[4];
    const float* W1 = (const float*)d_in[5];
    const float* b1 = (const float*)d_in[6];
    const float* W2 = (const float*)d_in[7];
    const float* b2 = (const float*)d_in[8];
    const float* W3 = (const float*)d_in[9];
    const float* b3 = (const float*)d_in[10];
    const float* Wm = (const float*)d_in[11];
    const float* bm = (const float*)d_in[12];
    const float* emb = (const float*)d_in[13];
    const float* Wp1 = (const float*)d_in[14];
    const float* bp1 = (const float*)d_in[15];
    const float* Wp2 = (const float*)d_in[16];
    const float* bp2 = (const float*)d_in[17];
    float* out = (float*)d_out;

    char* ws = (char*)d_ws;
    size_t off = 0;
    auto alloc = [&](size_t bytes) -> void* {
        void* p = ws + off;
        off = (off + bytes + 255) & ~(size_t)255;
        return p;
    };
    int*   row_ptr = (int*)alloc((size_t)(N + 1) * 4);
    float* dinv    = (float*)alloc((size_t)N * 4);
    int*   gstart  = (int*)alloc((size_t)(G + 1) * 4);
    int*   bkt     = (int*)alloc((size_t)NBKT * 4);
    int*   bbase   = (int*)alloc((size_t)(NBKT + 1) * 4);
    int*   bcur    = (int*)alloc((size_t)NBKT * 4);
    int*   ctr     = (int*)alloc(3 * 4);                 // dynamic chunk counters
    int*   colsS   = (int*)alloc((size_t)E * 4);
    float* psum    = (float*)alloc((size_t)G * 64 * 4);
    float* pmax    = (float*)alloc((size_t)G * 64 * 4);
    bfu*   Mb      = (bfu*)alloc((size_t)N * 64 * 2);    // bf16 GEMM output
    bfu*   hb      = (bfu*)alloc((size_t)N * 64 * 2);    // bf16 h' (agg output)
    float* fused   = (float*)alloc((size_t)G * 224 * 4);

    int2* tmp = (int2*)Mb;        // aliases Mb: dead until layer-1 GEMM writes it

    const int nbBin = (E + BIN_CHUNK - 1) / BIN_CHUNK;   // 391

    hipMemsetAsync(bkt, 0, (size_t)NBKT * 4, stream);
    hipMemsetAsync(ctr, 0, 3 * 4, stream);
    hipMemsetAsync(psum, 0, (size_t)G * 64 * 4, stream);
    hipMemsetAsync(pmax, 0, (size_t)G * 64 * 4, stream);

    k_bcnt<<<nbBin, 256, 0, stream>>>(ei, bkt, E);
    k_bscan<<<1, 256, 0, stream>>>(bkt, bbase, bcur);
    k_bin<<<nbBin, 256, 0, stream>>>(ei, ei + E, bcur, tmp, E);
    k_csr<<<NBKT, 256, 0, stream>>>(tmp, bbase, row_ptr, dinv, colsS, N, E);
    k_gb<<<(N + 256) / 256 + 1, 256, 0, stream>>>(batch, gstart, N, G);

    const int nTiles = N / 16;          // 25000
    // layer 1: M1 = (Dinv x) @ W1 (bf16) ; agg -> h1' bf16
    k_gemm_mfma<32, true, false><<<1563, 256, 0, stream>>>(x, W1, dinv, Mb, nTiles);
    k_agg_seg<0><<<2048, 256, 0, stream>>>(Mb, b1, row_ptr, colsS, dinv, batch,
                                           hb, psum, pmax, ctr);
    // layer 2 (A bf16)
    k_gemm_mfma<64, false, true><<<1563, 256, 0, stream>>>(hb, W2, dinv, Mb, nTiles);
    k_agg_seg<0><<<2048, 256, 0, stream>>>(Mb, b2, row_ptr, colsS, dinv, batch,
                                           hb, psum, pmax, ctr + 1);
    // layer 3: GEMM (A bf16) then agg+pool (atomics into psum/pmax)
    k_gemm_mfma<64, false, true><<<1563, 256, 0, stream>>>(hb, W3, dinv, Mb, nTiles);
    k_agg_seg<1><<<2048, 256, 0, stream>>>(Mb, b3, row_ptr, colsS, dinv, batch,
                                           hb, psum, pmax, ctr + 2);

    k_asm<<<512, 256, 0, stream>>>(psum, pmax, gstart, metadata, species, emb, Wm, bm,
                                   fused, G);
    k_pred_mfma<<<(G / 16 + 3) / 4, 256, 0, stream>>>(fused, Wp1, bp1, Wp2, bp2, out, G);
}

// Round 5
// 1094.175 us; speedup vs baseline: 1.1920x; 1.1920x over previous
//
#include <hip/hip_runtime.h>
#include <hip/hip_bf16.h>

#define N_NODES 400000
#define N_EDGES 1600000
#define N_GRAPHS 16384
#define CHUNK 32
#define NCHUNK (N_NODES / CHUNK)   // 12500

#define BSHIFT 11
#define BKT_N (1 << BSHIFT)                               // 2048 rows per bucket
#define NBKT ((N_NODES + BKT_N - 1) >> BSHIFT)            // 196 row-buckets
#define BIN_CHUNK 4096

typedef __attribute__((ext_vector_type(8))) short bf16x8;
typedef __attribute__((ext_vector_type(4))) float f32x4;
typedef unsigned short bfu;

__device__ __forceinline__ float rlane(float x, int k) {
    return __int_as_float(__builtin_amdgcn_readlane(__float_as_int(x), k));
}
__device__ __forceinline__ int rlanei(int x, int k) {
    return __builtin_amdgcn_readlane(x, k);
}

__device__ __forceinline__ short f2bf(float x) {  // RNE float -> bf16 bits
    unsigned u = __float_as_uint(x);
    unsigned r = (u + 0x7fffu + ((u >> 16) & 1u)) >> 16;
    return (short)r;
}
__device__ __forceinline__ float bf2f(short b) {
    return __uint_as_float(((unsigned)(unsigned short)b) << 16);
}
__device__ __forceinline__ float bfu2f(bfu b) {
    return __uint_as_float(((unsigned)b) << 16);
}

// ---- bucket counts: LDS histogram, ~196 global atomics per block ----
__global__ __launch_bounds__(256) void k_bcnt(const int* __restrict__ rows,
                                              int* __restrict__ bkt, int E) {
    __shared__ int l[NBKT];
    const int t = threadIdx.x;
    for (int i = t; i < NBKT; i += 256) l[i] = 0;
    __syncthreads();
    const int e0 = blockIdx.x * BIN_CHUNK;
#pragma unroll
    for (int k = 0; k < 16; ++k) {
        int e = e0 + k * 256 + t;
        if (e < E) atomicAdd(&l[rows[e] >> BSHIFT], 1);
    }
    __syncthreads();
    for (int i = t; i < NBKT; i += 256)
        if (l[i]) atomicAdd(&bkt[i], l[i]);
}

// ---- single-block exclusive scan over NBKT bucket counts ----
__global__ void k_bscan(const int* __restrict__ bkt, int* __restrict__ bbase,
                        int* __restrict__ bcur) {
    __shared__ int s[256];
    const int t = threadIdx.x;
    int v = (t < NBKT) ? bkt[t] : 0;
    s[t] = v; __syncthreads();
    for (int off = 1; off < 256; off <<= 1) {
        int x = (t >= off) ? s[t - off] : 0;
        __syncthreads();
        s[t] += x;
        __syncthreads();
    }
    int excl = s[t] - v;
    if (t < NBKT) { bbase[t] = excl; bcur[t] = excl; }
    if (t == NBKT) bbase[NBKT] = excl;   // = E
}

// ---- bin edges by row-bucket (LDS-combined reservations) ----
__global__ __launch_bounds__(256) void k_bin(const int* __restrict__ rows,
                                             const int* __restrict__ cols,
                                             int* __restrict__ bcur,
                                             int2* __restrict__ tmp, int E) {
    __shared__ int lcnt[NBKT];
    __shared__ int lbase[NBKT];
    const int t = threadIdx.x;
    const int e0 = blockIdx.x * BIN_CHUNK;
    for (int i = t; i < NBKT; i += 256) lcnt[i] = 0;
    __syncthreads();
    int r[16];
#pragma unroll
    for (int k = 0; k < 16; ++k) {
        int e = e0 + k * 256 + t;
        r[k] = (e < E) ? rows[e] : -1;
        if (r[k] >= 0) atomicAdd(&lcnt[r[k] >> BSHIFT], 1);
    }
    __syncthreads();
    for (int i = t; i < NBKT; i += 256) lbase[i] = atomicAdd(&bcur[i], lcnt[i]);
    __syncthreads();
    for (int i = t; i < NBKT; i += 256) lcnt[i] = 0;
    __syncthreads();
#pragma unroll
    for (int k = 0; k < 16; ++k) {
        int e = e0 + k * 256 + t;
        if (r[k] >= 0) {
            int b = r[k] >> BSHIFT;
            int p = lbase[b] + atomicAdd(&lcnt[b], 1);
            tmp[p] = make_int2(r[k], cols[e]);
        }
    }
}

// ---- per-bucket CSR build: row_ptr + dinv + cols scatter, all block-local ----
__global__ __launch_bounds__(256) void k_csr(const int2* __restrict__ tmp,
                                             const int* __restrict__ bbase,
                                             int* __restrict__ row_ptr,
                                             float* __restrict__ dinv,
                                             int* __restrict__ colsOut,
                                             int N, int E) {
    __shared__ int lcnt[BKT_N];
    __shared__ int lofs[BKT_N];
    __shared__ int tsum[256];
    const int t = threadIdx.x;
    const int b = blockIdx.x;
    const int r0 = b << BSHIFT;
    const int S = bbase[b];
    const int T = bbase[b + 1];
    for (int i = t; i < BKT_N; i += 256) lcnt[i] = 0;
    __syncthreads();
    for (int e = S + t; e < T; e += 256) atomicAdd(&lcnt[tmp[e].x - r0], 1);
    __syncthreads();
    // block scan of 2048 counts: 8 sequential per thread + 256-thread scan
    const int base8 = t * 8;
    int vals[8];
    int run = 0;
#pragma unroll
    for (int k = 0; k < 8; ++k) { vals[k] = run; run += lcnt[base8 + k]; }
    tsum[t] = run;
    __syncthreads();
    for (int off = 1; off < 256; off <<= 1) {
        int x = (t >= off) ? tsum[t - off] : 0;
        __syncthreads();
        tsum[t] += x;
        __syncthreads();
    }
    const int texcl = tsum[t] - run;
#pragma unroll
    for (int k = 0; k < 8; ++k) lofs[base8 + k] = texcl + vals[k];
    __syncthreads();
    for (int i = t; i < BKT_N; i += 256) {
        int node = r0 + i;
        if (node < N) {
            row_ptr[node] = S + lofs[i];
            dinv[node] = rsqrtf((float)lcnt[i] + 1.0f);
        }
    }
    if (b == 0 && t == 0) row_ptr[N] = E;
    __syncthreads();
    // scatter cols; lofs doubles as LDS cursor
    for (int e = S + t; e < T; e += 256) {
        int2 rc = tmp[e];
        int pos = S + atomicAdd(&lofs[rc.x - r0], 1);
        colsOut[pos] = rc.y;
    }
}

// ---- gstart from sorted batch via boundary detection (no atomics) ----
__global__ void k_gb(const int* __restrict__ batch, int* __restrict__ gstart,
                     int N, int G) {
    int i = blockIdx.x * blockDim.x + threadIdx.x;
    if (i <= N) {
        int b = (i < N) ? batch[i] : G;
        int prev = (i == 0) ? -1 : batch[i - 1];
        for (int g = prev + 1; g <= b; ++g) gstart[g] = i;
    }
}

// ---- MFMA GEMM (grid-stride over 16-node tiles).
// ABF16=0: A fp32, split hi/lo (3 MFMAs per nt,kt), optional dinv prescale.
// ABF16=1: A already bf16 (2 MFMAs per nt,kt). Output always bf16.
template <int IN_D, bool PRESCALE, bool ABF16>
__global__ __launch_bounds__(256, 4) void k_gemm_mfma(
        const void* __restrict__ in_, const float* __restrict__ W,
        const float* __restrict__ dinv, bfu* __restrict__ out, int nTiles) {
    constexpr int KT = IN_D / 32;
    const int lane = threadIdx.x & 63;
    const int m = lane & 15;
    const int q = lane >> 4;

    bf16x8 Bhi[4][KT], Blo[4][KT];
#pragma unroll
    for (int nt = 0; nt < 4; ++nt) {
#pragma unroll
        for (int kt = 0; kt < KT; ++kt) {
#pragma unroll
            for (int j = 0; j < 8; ++j) {
                int k = kt * 32 + q * 8 + j;
                float w = W[k * 64 + nt * 16 + m];
                short hi = f2bf(w);
                Bhi[nt][kt][j] = hi;
                Blo[nt][kt][j] = f2bf(w - bf2f(hi));
            }
        }
    }

    const int wv = (blockIdx.x * 256 + threadIdx.x) >> 6;
    const int nwv = (gridDim.x * 256) >> 6;

    for (int tile = wv; tile < nTiles; tile += nwv) {
        const int node0 = tile * 16;
        f32x4 C[4];
#pragma unroll
        for (int nt = 0; nt < 4; ++nt) C[nt] = (f32x4){0.f, 0.f, 0.f, 0.f};

        if (ABF16) {
            const bfu* rowb = (const bfu*)in_ + (size_t)(node0 + m) * IN_D + q * 8;
            bf16x8 A[KT];
#pragma unroll
            for (int kt = 0; kt < KT; ++kt) A[kt] = *(const bf16x8*)(rowb + kt * 32);
#pragma unroll
            for (int nt = 0; nt < 4; ++nt) {
#pragma unroll
                for (int kt = 0; kt < KT; ++kt) {
                    C[nt] = __builtin_amdgcn_mfma_f32_16x16x32_bf16(A[kt], Bhi[nt][kt], C[nt], 0, 0, 0);
                    C[nt] = __builtin_amdgcn_mfma_f32_16x16x32_bf16(A[kt], Blo[nt][kt], C[nt], 0, 0, 0);
                }
            }
        } else {
            const float dv = PRESCALE ? dinv[node0 + m] : 1.0f;
            const float* rowp = (const float*)in_ + (size_t)(node0 + m) * IN_D + q * 8;
            bf16x8 Ahi[KT], Alo[KT];
#pragma unroll
            for (int kt = 0; kt < KT; ++kt) {
                f32x4 a0 = *(const f32x4*)(rowp + kt * 32);
                f32x4 a1 = *(const f32x4*)(rowp + kt * 32 + 4);
#pragma unroll
                for (int j = 0; j < 4; ++j) {
                    float xx = PRESCALE ? dv * a0[j] : a0[j];
                    short hi = f2bf(xx);
                    Ahi[kt][j] = hi;
                    Alo[kt][j] = f2bf(xx - bf2f(hi));
                }
#pragma unroll
                for (int j = 0; j < 4; ++j) {
                    float xx = PRESCALE ? dv * a1[j] : a1[j];
                    short hi = f2bf(xx);
                    Ahi[kt][4 + j] = hi;
                    Alo[kt][4 + j] = f2bf(xx - bf2f(hi));
                }
            }
#pragma unroll
            for (int nt = 0; nt < 4; ++nt) {
#pragma unroll
                for (int kt = 0; kt < KT; ++kt) {
                    C[nt] = __builtin_amdgcn_mfma_f32_16x16x32_bf16(Ahi[kt], Bhi[nt][kt], C[nt], 0, 0, 0);
                    C[nt] = __builtin_amdgcn_mfma_f32_16x16x32_bf16(Ahi[kt], Blo[nt][kt], C[nt], 0, 0, 0);
                    C[nt] = __builtin_amdgcn_mfma_f32_16x16x32_bf16(Alo[kt], Bhi[nt][kt], C[nt], 0, 0, 0);
                }
            }
        }

        bfu* op = out + (size_t)node0 * 64;
#pragma unroll
        for (int nt = 0; nt < 4; ++nt) {
#pragma unroll
            for (int r = 0; r < 4; ++r) {
                op[(size_t)(q * 4 + r) * 64 + nt * 16 + m] = (bfu)f2bf(C[nt][r]);
            }
        }
    }
}

// ==== segmented-stream aggregation over bf16 M rows ====
// R5 = exact R1 agg body (16-deep ring — 32 spills to scratch, R4; col window
// in VGPRs with per-edge readlane — per-edge memory loads serialize, R3)
// + dynamic chunk scheduling (lane-0 atomicAdd, 2048 blocks => occupancy
// pinned near 100% until drain; R1's static 1-chunk/wave gave 59%).
// POOL=0: out[i] = bf16( dinv[i] * relu(dinv[i]*(M_i + sum_j M_j) + b) )
// POOL=1: h3 = relu(...) pooled per graph-run -> atomics into psum/pmax.
template <int POOL>
__global__ __launch_bounds__(256, 8) void k_agg_seg(
        const bfu* __restrict__ M, const float* __restrict__ bias,
        const int* __restrict__ row_ptr, const int* __restrict__ cols,
        const float* __restrict__ dinv, const int* __restrict__ batch,
        bfu* __restrict__ out, float* __restrict__ psum,
        float* __restrict__ pmax, int* __restrict__ ctr) {
    const int lane = threadIdx.x & 63;
    const float b = bias[lane];
    const bfu* Ml = M + lane;   // per-lane base; row r at Ml[r*64]

    for (;;) {
        int cw = 0;
        if (lane == 0) cw = atomicAdd(ctr, 1);
        const int c = __builtin_amdgcn_readfirstlane(cw);
        if (c >= NCHUNK) break;

        const int i0 = c * CHUNK;
        const int rpn = row_ptr[i0 + min(lane, CHUNK - 1) + 1];
        const int S = row_ptr[i0];
        const int ne = rlanei(rpn, CHUNK - 1) - S;
        const float dvv = dinv[i0 + min(lane, CHUNK - 1)];
        const int bvv = POOL ? batch[i0 + min(lane, CHUNK - 1)] : 0;

        int node = 0;
        int bnd = rlanei(rpn, 0) - S;
        float acc = 0.0f;
        float selfA = bfu2f(Ml[(size_t)i0 * 64]);
        float selfB = bfu2f(Ml[(size_t)(i0 + 1) * 64]);
        float selfC = bfu2f(Ml[(size_t)(i0 + 2) * 64]);
        int gcur = POOL ? rlanei(bvv, 0) : 0;
        float rsum = 0.0f, rmax = 0.0f;

        auto flush = [&]() {
            if (POOL) {
                atomicAdd(&psum[(size_t)gcur * 64 + lane], rsum);
                atomicMax((int*)&pmax[(size_t)gcur * 64 + lane], __float_as_int(rmax));
            }
        };
        auto finalize = [&]() {
            const float d = rlane(dvv, node);
            const float h = fmaxf(fmaf(d, selfA + acc, b), 0.0f);
            if (POOL) {
                const int g = rlanei(bvv, node);
                if (g != gcur) { flush(); gcur = g; rsum = 0.0f; rmax = 0.0f; }
                rsum += h;
                rmax = fmaxf(rmax, h);
            } else {
                out[(size_t)(i0 + node) * 64 + lane] = (bfu)f2bf(d * h);
            }
            acc = 0.0f;
            selfA = selfB;
            selfB = selfC;
            if (node + 3 < CHUNK) selfC = bfu2f(Ml[(size_t)(i0 + node + 3) * 64]);
            ++node;
            if (node < CHUNK) bnd = rlanei(rpn, node) - S;
        };

        if (ne > 0) {
            int bidx = 0;
            int a0 = S + lane, a1 = S + 64 + lane;
            int colv0 = (a0 < S + ne) ? cols[a0] : 0;
            int colv1 = (a1 < S + ne) ? cols[a1] : 0;
            unsigned ubuf[16];
#pragma unroll
            for (int k = 0; k < 16; ++k) {
                int e = min(k, ne - 1);
                int cc = rlanei(colv0, e);
                ubuf[k] = Ml[(size_t)cc * 64];
            }

            int j = 0;
            while (j + 16 <= ne) {
#pragma unroll
                for (int k = 0; k < 16; ++k) {
                    const int jj = j + k;
                    if ((jj & 63) == 0 && jj != 0) {
                        colv0 = colv1;
                        ++bidx;
                        int ad = S + (bidx + 1) * 64 + lane;
                        colv1 = (ad < S + ne) ? cols[ad] : 0;
                    }
                    while (jj == bnd) finalize();
                    acc += __uint_as_float(ubuf[k] << 16);
                    int ec = min(jj + 16, ne - 1);
                    int src = ((ec >> 6) == bidx) ? colv0 : colv1;
                    int cc = rlanei(src, ec & 63);
                    ubuf[k] = Ml[(size_t)cc * 64];
                }
                j += 16;
            }
            for (; j < ne; ++j) {
                while (j == bnd) finalize();
                acc += __uint_as_float(ubuf[j & 15] << 16);
            }
        }
        while (node < CHUNK) finalize();
        flush();
    }
}

// ---- assemble fused vector: [mean | max | relu(meta@Wm+bm) | emb | pad] ----
__global__ __launch_bounds__(256) void k_asm(
        const float* __restrict__ psum, const float* __restrict__ pmax,
        const int* __restrict__ gstart, const float* __restrict__ metadata,
        const int* __restrict__ species, const float* __restrict__ emb,
        const float* __restrict__ Wm, const float* __restrict__ bm,
        float* __restrict__ fused, int G) {
    const int lane = threadIdx.x & 63;
    int wv = (blockIdx.x * blockDim.x + threadIdx.x) >> 6;
    const int nw = (gridDim.x * blockDim.x) >> 6;
    const float bmr = bm[lane];
    float wmr[16];
#pragma unroll
    for (int k = 0; k < 16; ++k) wmr[k] = Wm[k * 64 + lane];
    for (int g = wv; g < G; g += nw) {
        float gc = (float)(gstart[g + 1] - gstart[g]);
        float mean = psum[(size_t)g * 64 + lane] / fmaxf(gc, 1.0f);
        float mx = pmax[(size_t)g * 64 + lane];
        float md = lane < 16 ? metadata[(size_t)g * 16 + lane] : 0.0f;
        float mval = bmr;
#pragma unroll
        for (int k = 0; k < 16; ++k) mval = fmaf(rlane(md, k), wmr[k], mval);
        mval = fmaxf(mval, 0.0f);
        const int sid = species[g];
        float* fr = fused + (size_t)g * 224;
        fr[lane] = mean;
        fr[64 + lane] = mx;
        fr[128 + lane] = mval;
        if (lane < 16) fr[192 + lane] = emb[(size_t)sid * 16 + lane];
        else if (lane < 32) fr[192 + lane] = 0.0f;
    }
}

// ---- MFMA predictor head ----
__global__ __launch_bounds__(256, 2) void k_pred_mfma(
        const float* __restrict__ fused, const float* __restrict__ Wp1,
        const float* __restrict__ bp1, const float* __restrict__ Wp2,
        const float* __restrict__ bp2, float* __restrict__ out, int G) {
    __shared__ __align__(16) short Whi[64 * 232];
    __shared__ __align__(16) short Wlo[64 * 232];
    const int t = threadIdx.x;
    for (int idx = t; idx < 64 * 232; idx += 256) {
        int n = idx / 232;
        int k = idx % 232;
        float w = (k < 208) ? Wp1[(size_t)k * 64 + n] : 0.0f;
        short hi = f2bf(w);
        Whi[n * 232 + k] = hi;
        Wlo[n * 232 + k] = f2bf(w - bf2f(hi));
    }
    __syncthreads();

    const int lane = t & 63;
    const int wave = t >> 6;
    const int m = lane & 15;
    const int q = lane >> 4;
    const int g0 = (blockIdx.x * 4 + wave) * 16;
    if (g0 >= G) return;

    const float* rowp = fused + (size_t)(g0 + m) * 224 + q * 8;

    f32x4 C[4];
#pragma unroll
    for (int nt = 0; nt < 4; ++nt) C[nt] = (f32x4){0.f, 0.f, 0.f, 0.f};

#pragma unroll
    for (int kt = 0; kt < 7; ++kt) {
        f32x4 a0 = *(const f32x4*)(rowp + kt * 32);
        f32x4 a1 = *(const f32x4*)(rowp + kt * 32 + 4);
        bf16x8 Ahi, Alo;
#pragma unroll
        for (int j = 0; j < 4; ++j) {
            short hi = f2bf(a0[j]);
            Ahi[j] = hi;
            Alo[j] = f2bf(a0[j] - bf2f(hi));
        }
#pragma unroll
        for (int j = 0; j < 4; ++j) {
            short hi = f2bf(a1[j]);
            Ahi[4 + j] = hi;
            Alo[4 + j] = f2bf(a1[j] - bf2f(hi));
        }
#pragma unroll
        for (int nt = 0; nt < 4; ++nt) {
            const int boff = (nt * 16 + m) * 232 + kt * 32 + q * 8;
            bf16x8 Bh = *(const bf16x8*)&Whi[boff];
            bf16x8 Bl = *(const bf16x8*)&Wlo[boff];
            C[nt] = __builtin_amdgcn_mfma_f32_16x16x32_bf16(Ahi, Bh, C[nt], 0, 0, 0);
            C[nt] = __builtin_amdgcn_mfma_f32_16x16x32_bf16(Ahi, Bl, C[nt], 0, 0, 0);
            C[nt] = __builtin_amdgcn_mfma_f32_16x16x32_bf16(Alo, Bh, C[nt], 0, 0, 0);
        }
    }

    float wp2r[4], bp1r[4];
#pragma unroll
    for (int nt = 0; nt < 4; ++nt) {
        wp2r[nt] = Wp2[nt * 16 + m];
        bp1r[nt] = bp1[nt * 16 + m];
    }
    const float bp2v = bp2[0];
    float s[4];
#pragma unroll
    for (int r = 0; r < 4; ++r) {
        float acc = 0.0f;
#pragma unroll
        for (int nt = 0; nt < 4; ++nt)
            acc += fmaxf(C[nt][r] + bp1r[nt], 0.0f) * wp2r[nt];
        s[r] = acc;
    }
#pragma unroll
    for (int off = 1; off < 16; off <<= 1) {
#pragma unroll
        for (int r = 0; r < 4; ++r) s[r] += __shfl_xor(s[r], off);
    }
    if (m == 0) {
#pragma unroll
        for (int r = 0; r < 4; ++r) out[g0 + q * 4 + r] = s[r] + bp2v;
    }
}

extern "C" void kernel_launch(void* const* d_in, const int* in_sizes, int n_in,
                              void* d_out, int out_size, void* d_ws, size_t ws_size,
                              hipStream_t stream) {
    const int N = N_NODES, E = N_EDGES, G = N_GRAPHS;

    const float* x        = (const float*)d_in[0];
    const float* metadata = (const float*)d_in[1];
    const int*   ei       = (const int*)d_in[2];
    const int*   batch    = (const int*)d_in[3];
    const int*   species  = (const int*)d_in[4];
    const float* W1 = (const float*)d_in[5];
    const float* b1 = (const float*)d_in[6];
    const float* W2 = (const float*)d_in[7];
    const float* b2 = (const float*)d_in[8];
    const float* W3 = (const float*)d_in[9];
    const float* b3 = (const float*)d_in[10];
    const float* Wm = (const float*)d_in[11];
    const float* bm = (const float*)d_in[12];
    const float* emb = (const float*)d_in[13];
    const float* Wp1 = (const float*)d_in[14];
    const float* bp1 = (const float*)d_in[15];
    const float* Wp2 = (const float*)d_in[16];
    const float* bp2 = (const float*)d_in[17];
    float* out = (float*)d_out;

    char* ws = (char*)d_ws;
    size_t off = 0;
    auto alloc = [&](size_t bytes) -> void* {
        void* p = ws + off;
        off = (off + bytes + 255) & ~(size_t)255;
        return p;
    };
    int*   row_ptr = (int*)alloc((size_t)(N + 1) * 4);
    float* dinv    = (float*)alloc((size_t)N * 4);
    int*   gstart  = (int*)alloc((size_t)(G + 1) * 4);
    int*   bkt     = (int*)alloc((size_t)NBKT * 4);
    int*   bbase   = (int*)alloc((size_t)(NBKT + 1) * 4);
    int*   bcur    = (int*)alloc((size_t)NBKT * 4);
    int*   ctr     = (int*)alloc(3 * 4);                 // dynamic chunk counters
    int*   colsS   = (int*)alloc((size_t)E * 4);
    float* psum    = (float*)alloc((size_t)G * 64 * 4);
    float* pmax    = (float*)alloc((size_t)G * 64 * 4);
    bfu*   Mb      = (bfu*)alloc((size_t)N * 64 * 2);    // bf16 GEMM output
    bfu*   hb      = (bfu*)alloc((size_t)N * 64 * 2);    // bf16 h' (agg output)
    float* fused   = (float*)alloc((size_t)G * 224 * 4);

    int2* tmp = (int2*)Mb;        // aliases Mb: dead until layer-1 GEMM writes it

    const int nbBin = (E + BIN_CHUNK - 1) / BIN_CHUNK;   // 391

    hipMemsetAsync(bkt, 0, (size_t)NBKT * 4, stream);
    hipMemsetAsync(ctr, 0, 3 * 4, stream);
    hipMemsetAsync(psum, 0, (size_t)G * 64 * 4, stream);
    hipMemsetAsync(pmax, 0, (size_t)G * 64 * 4, stream);

    k_bcnt<<<nbBin, 256, 0, stream>>>(ei, bkt, E);
    k_bscan<<<1, 256, 0, stream>>>(bkt, bbase, bcur);
    k_bin<<<nbBin, 256, 0, stream>>>(ei, ei + E, bcur, tmp, E);
    k_csr<<<NBKT, 256, 0, stream>>>(tmp, bbase, row_ptr, dinv, colsS, N, E);
    k_gb<<<(N + 256) / 256 + 1, 256, 0, stream>>>(batch, gstart, N, G);

    const int nTiles = N / 16;          // 25000
    // layer 1: M1 = (Dinv x) @ W1 (bf16) ; agg -> h1' bf16
    k_gemm_mfma<32, true, false><<<1563, 256, 0, stream>>>(x, W1, dinv, Mb, nTiles);
    k_agg_seg<0><<<2048, 256, 0, stream>>>(Mb, b1, row_ptr, colsS, dinv, batch,
                                           hb, psum, pmax, ctr);
    // layer 2 (A bf16)
    k_gemm_mfma<64, false, true><<<1563, 256, 0, stream>>>(hb, W2, dinv, Mb, nTiles);
    k_agg_seg<0><<<2048, 256, 0, stream>>>(Mb, b2, row_ptr, colsS, dinv, batch,
                                           hb, psum, pmax, ctr + 1);
    // layer 3: GEMM (A bf16) then agg+pool (atomics into psum/pmax)
    k_gemm_mfma<64, false, true><<<1563, 256, 0, stream>>>(hb, W3, dinv, Mb, nTiles);
    k_agg_seg<1><<<2048, 256, 0, stream>>>(Mb, b3, row_ptr, colsS, dinv, batch,
                                           hb, psum, pmax, ctr + 2);

    k_asm<<<512, 256, 0, stream>>>(psum, pmax, gstart, metadata, species, emb, Wm, bm,
                                   fused, G);
    k_pred_mfma<<<(G / 16 + 3) / 4, 256, 0, stream>>>(fused, Wp1, bp1, Wp2, bp2, out, G);
}

// Round 6
// 631.839 us; speedup vs baseline: 2.0643x; 1.7317x over previous
//
#include <hip/hip_runtime.h>
#include <hip/hip_bf16.h>

#define N_NODES 400000
#define N_EDGES 1600000
#define N_GRAPHS 16384
#define CHUNK 32
#define NCHUNK (N_NODES / CHUNK)   // 12500

#define BSHIFT 11
#define BKT_N (1 << BSHIFT)                               // 2048 rows per bucket
#define NBKT ((N_NODES + BKT_N - 1) >> BSHIFT)            // 196 row-buckets
#define BIN_CHUNK 4096

typedef __attribute__((ext_vector_type(8))) short bf16x8;
typedef __attribute__((ext_vector_type(4))) float f32x4;
typedef unsigned short bfu;

__device__ __forceinline__ float rlane(float x, int k) {
    return __int_as_float(__builtin_amdgcn_readlane(__float_as_int(x), k));
}
__device__ __forceinline__ int rlanei(int x, int k) {
    return __builtin_amdgcn_readlane(x, k);
}

__device__ __forceinline__ short f2bf(float x) {  // RNE float -> bf16 bits
    unsigned u = __float_as_uint(x);
    unsigned r = (u + 0x7fffu + ((u >> 16) & 1u)) >> 16;
    return (short)r;
}
__device__ __forceinline__ float bf2f(short b) {
    return __uint_as_float(((unsigned)(unsigned short)b) << 16);
}
__device__ __forceinline__ float bfu2f(bfu b) {
    return __uint_as_float(((unsigned)b) << 16);
}

// ---- bucket counts: LDS histogram, ~196 global atomics per block ----
__global__ __launch_bounds__(256) void k_bcnt(const int* __restrict__ rows,
                                              int* __restrict__ bkt, int E) {
    __shared__ int l[NBKT];
    const int t = threadIdx.x;
    for (int i = t; i < NBKT; i += 256) l[i] = 0;
    __syncthreads();
    const int e0 = blockIdx.x * BIN_CHUNK;
#pragma unroll
    for (int k = 0; k < 16; ++k) {
        int e = e0 + k * 256 + t;
        if (e < E) atomicAdd(&l[rows[e] >> BSHIFT], 1);
    }
    __syncthreads();
    for (int i = t; i < NBKT; i += 256)
        if (l[i]) atomicAdd(&bkt[i], l[i]);
}

// ---- single-block exclusive scan over NBKT bucket counts ----
__global__ void k_bscan(const int* __restrict__ bkt, int* __restrict__ bbase,
                        int* __restrict__ bcur) {
    __shared__ int s[256];
    const int t = threadIdx.x;
    int v = (t < NBKT) ? bkt[t] : 0;
    s[t] = v; __syncthreads();
    for (int off = 1; off < 256; off <<= 1) {
        int x = (t >= off) ? s[t - off] : 0;
        __syncthreads();
        s[t] += x;
        __syncthreads();
    }
    int excl = s[t] - v;
    if (t < NBKT) { bbase[t] = excl; bcur[t] = excl; }
    if (t == NBKT) bbase[NBKT] = excl;   // = E
}

// ---- bin edges by row-bucket (LDS-combined reservations) ----
__global__ __launch_bounds__(256) void k_bin(const int* __restrict__ rows,
                                             const int* __restrict__ cols,
                                             int* __restrict__ bcur,
                                             int2* __restrict__ tmp, int E) {
    __shared__ int lcnt[NBKT];
    __shared__ int lbase[NBKT];
    const int t = threadIdx.x;
    const int e0 = blockIdx.x * BIN_CHUNK;
    for (int i = t; i < NBKT; i += 256) lcnt[i] = 0;
    __syncthreads();
    int r[16];
#pragma unroll
    for (int k = 0; k < 16; ++k) {
        int e = e0 + k * 256 + t;
        r[k] = (e < E) ? rows[e] : -1;
        if (r[k] >= 0) atomicAdd(&lcnt[r[k] >> BSHIFT], 1);
    }
    __syncthreads();
    for (int i = t; i < NBKT; i += 256) lbase[i] = atomicAdd(&bcur[i], lcnt[i]);
    __syncthreads();
    for (int i = t; i < NBKT; i += 256) lcnt[i] = 0;
    __syncthreads();
#pragma unroll
    for (int k = 0; k < 16; ++k) {
        int e = e0 + k * 256 + t;
        if (r[k] >= 0) {
            int b = r[k] >> BSHIFT;
            int p = lbase[b] + atomicAdd(&lcnt[b], 1);
            tmp[p] = make_int2(r[k], cols[e]);
        }
    }
}

// ---- per-bucket CSR build: row_ptr + dinv + cols scatter, all block-local ----
__global__ __launch_bounds__(256) void k_csr(const int2* __restrict__ tmp,
                                             const int* __restrict__ bbase,
                                             int* __restrict__ row_ptr,
                                             float* __restrict__ dinv,
                                             int* __restrict__ colsOut,
                                             int N, int E) {
    __shared__ int lcnt[BKT_N];
    __shared__ int lofs[BKT_N];
    __shared__ int tsum[256];
    const int t = threadIdx.x;
    const int b = blockIdx.x;
    const int r0 = b << BSHIFT;
    const int S = bbase[b];
    const int T = bbase[b + 1];
    for (int i = t; i < BKT_N; i += 256) lcnt[i] = 0;
    __syncthreads();
    for (int e = S + t; e < T; e += 256) atomicAdd(&lcnt[tmp[e].x - r0], 1);
    __syncthreads();
    // block scan of 2048 counts: 8 sequential per thread + 256-thread scan
    const int base8 = t * 8;
    int vals[8];
    int run = 0;
#pragma unroll
    for (int k = 0; k < 8; ++k) { vals[k] = run; run += lcnt[base8 + k]; }
    tsum[t] = run;
    __syncthreads();
    for (int off = 1; off < 256; off <<= 1) {
        int x = (t >= off) ? tsum[t - off] : 0;
        __syncthreads();
        tsum[t] += x;
        __syncthreads();
    }
    const int texcl = tsum[t] - run;
#pragma unroll
    for (int k = 0; k < 8; ++k) lofs[base8 + k] = texcl + vals[k];
    __syncthreads();
    for (int i = t; i < BKT_N; i += 256) {
        int node = r0 + i;
        if (node < N) {
            row_ptr[node] = S + lofs[i];
            dinv[node] = rsqrtf((float)lcnt[i] + 1.0f);
        }
    }
    if (b == 0 && t == 0) row_ptr[N] = E;
    __syncthreads();
    // scatter cols; lofs doubles as LDS cursor
    for (int e = S + t; e < T; e += 256) {
        int2 rc = tmp[e];
        int pos = S + atomicAdd(&lofs[rc.x - r0], 1);
        colsOut[pos] = rc.y;
    }
}

// ---- gstart from sorted batch via boundary detection (no atomics) ----
__global__ void k_gb(const int* __restrict__ batch, int* __restrict__ gstart,
                     int N, int G) {
    int i = blockIdx.x * blockDim.x + threadIdx.x;
    if (i <= N) {
        int b = (i < N) ? batch[i] : G;
        int prev = (i == 0) ? -1 : batch[i - 1];
        for (int g = prev + 1; g <= b; ++g) gstart[g] = i;
    }
}

// ---- MFMA GEMM (grid-stride over 16-node tiles).
// ABF16=0: A fp32, split hi/lo (3 MFMAs per nt,kt), optional dinv prescale.
// ABF16=1: A already bf16 (2 MFMAs per nt,kt). Output always bf16.
template <int IN_D, bool PRESCALE, bool ABF16>
__global__ __launch_bounds__(256, 4) void k_gemm_mfma(
        const void* __restrict__ in_, const float* __restrict__ W,
        const float* __restrict__ dinv, bfu* __restrict__ out, int nTiles) {
    constexpr int KT = IN_D / 32;
    const int lane = threadIdx.x & 63;
    const int m = lane & 15;
    const int q = lane >> 4;

    bf16x8 Bhi[4][KT], Blo[4][KT];
#pragma unroll
    for (int nt = 0; nt < 4; ++nt) {
#pragma unroll
        for (int kt = 0; kt < KT; ++kt) {
#pragma unroll
            for (int j = 0; j < 8; ++j) {
                int k = kt * 32 + q * 8 + j;
                float w = W[k * 64 + nt * 16 + m];
                short hi = f2bf(w);
                Bhi[nt][kt][j] = hi;
                Blo[nt][kt][j] = f2bf(w - bf2f(hi));
            }
        }
    }

    const int wv = (blockIdx.x * 256 + threadIdx.x) >> 6;
    const int nwv = (gridDim.x * 256) >> 6;

    for (int tile = wv; tile < nTiles; tile += nwv) {
        const int node0 = tile * 16;
        f32x4 C[4];
#pragma unroll
        for (int nt = 0; nt < 4; ++nt) C[nt] = (f32x4){0.f, 0.f, 0.f, 0.f};

        if (ABF16) {
            const bfu* rowb = (const bfu*)in_ + (size_t)(node0 + m) * IN_D + q * 8;
            bf16x8 A[KT];
#pragma unroll
            for (int kt = 0; kt < KT; ++kt) A[kt] = *(const bf16x8*)(rowb + kt * 32);
#pragma unroll
            for (int nt = 0; nt < 4; ++nt) {
#pragma unroll
                for (int kt = 0; kt < KT; ++kt) {
                    C[nt] = __builtin_amdgcn_mfma_f32_16x16x32_bf16(A[kt], Bhi[nt][kt], C[nt], 0, 0, 0);
                    C[nt] = __builtin_amdgcn_mfma_f32_16x16x32_bf16(A[kt], Blo[nt][kt], C[nt], 0, 0, 0);
                }
            }
        } else {
            const float dv = PRESCALE ? dinv[node0 + m] : 1.0f;
            const float* rowp = (const float*)in_ + (size_t)(node0 + m) * IN_D + q * 8;
            bf16x8 Ahi[KT], Alo[KT];
#pragma unroll
            for (int kt = 0; kt < KT; ++kt) {
                f32x4 a0 = *(const f32x4*)(rowp + kt * 32);
                f32x4 a1 = *(const f32x4*)(rowp + kt * 32 + 4);
#pragma unroll
                for (int j = 0; j < 4; ++j) {
                    float xx = PRESCALE ? dv * a0[j] : a0[j];
                    short hi = f2bf(xx);
                    Ahi[kt][j] = hi;
                    Alo[kt][j] = f2bf(xx - bf2f(hi));
                }
#pragma unroll
                for (int j = 0; j < 4; ++j) {
                    float xx = PRESCALE ? dv * a1[j] : a1[j];
                    short hi = f2bf(xx);
                    Ahi[kt][4 + j] = hi;
                    Alo[kt][4 + j] = f2bf(xx - bf2f(hi));
                }
            }
#pragma unroll
            for (int nt = 0; nt < 4; ++nt) {
#pragma unroll
                for (int kt = 0; kt < KT; ++kt) {
                    C[nt] = __builtin_amdgcn_mfma_f32_16x16x32_bf16(Ahi[kt], Bhi[nt][kt], C[nt], 0, 0, 0);
                    C[nt] = __builtin_amdgcn_mfma_f32_16x16x32_bf16(Ahi[kt], Blo[nt][kt], C[nt], 0, 0, 0);
                    C[nt] = __builtin_amdgcn_mfma_f32_16x16x32_bf16(Alo[kt], Bhi[nt][kt], C[nt], 0, 0, 0);
                }
            }
        }

        bfu* op = out + (size_t)node0 * 64;
#pragma unroll
        for (int nt = 0; nt < 4; ++nt) {
#pragma unroll
            for (int r = 0; r < 4; ++r) {
                op[(size_t)(q * 4 + r) * 64 + nt * 16 + m] = (bfu)f2bf(C[nt][r]);
            }
        }
    }
}

// ==== segmented-stream aggregation over bf16 M rows, dual-chunk per wave ====
// R6: exact R1 per-stream body (16-deep VGPR ring, col window in VGPRs with
// per-edge readlane; NO per-edge memory loads [R3], NO ring>16 [R4 spill],
// NO dynamic atomic scheduler [R5 poison]). Wave w owns chunks {2w, 2w+1};
// the two streams interleave at 16-edge-block granularity -> ~32 outstanding
// gathers per wave and 2x issue-to-use distance. Static grid, 1563 blocks.
// POOL=0: out[i] = bf16( dinv[i] * relu(dinv[i]*(M_i + sum_j M_j) + b) )
// POOL=1: h3 = relu(...) pooled per graph-run -> atomics into psum/pmax.

#define AGG_FLUSH(sfx)                                                          \
    if (POOL) {                                                                 \
        atomicAdd(&psum[(size_t)gcur##sfx * 64 + lane], rsum##sfx);             \
        atomicMax((int*)&pmax[(size_t)gcur##sfx * 64 + lane],                   \
                  __float_as_int(rmax##sfx));                                   \
    }

#define AGG_FINALIZE(sfx) {                                                     \
    const float d_ = rlane(dvv##sfx, node##sfx);                                \
    const float h_ = fmaxf(fmaf(d_, selfA##sfx + acc##sfx, b), 0.0f);           \
    if (POOL) {                                                                 \
        const int g_ = rlanei(bvv##sfx, node##sfx);                             \
        if (g_ != gcur##sfx) {                                                  \
            AGG_FLUSH(sfx);                                                     \
            gcur##sfx = g_; rsum##sfx = 0.0f; rmax##sfx = 0.0f;                 \
        }                                                                       \
        rsum##sfx += h_;                                                        \
        rmax##sfx = fmaxf(rmax##sfx, h_);                                       \
    } else {                                                                    \
        out[(size_t)(i0##sfx + node##sfx) * 64 + lane] = (bfu)f2bf(d_ * h_);    \
    }                                                                           \
    acc##sfx = 0.0f;                                                            \
    selfA##sfx = selfB##sfx;                                                    \
    selfB##sfx = selfC##sfx;                                                    \
    if (node##sfx + 3 < CHUNK)                                                  \
        selfC##sfx = bfu2f(Ml[(size_t)(i0##sfx + node##sfx + 3) * 64]);         \
    ++node##sfx;                                                                \
    if (node##sfx < CHUNK) bnd##sfx = rlanei(rpn##sfx, node##sfx) - S##sfx; }

#define AGG_INIT(sfx, cval)                                                     \
    const int i0##sfx = (cval) * CHUNK;                                         \
    const int rpn##sfx = row_ptr[i0##sfx + min(lane, CHUNK - 1) + 1];           \
    const int S##sfx = row_ptr[i0##sfx];                                        \
    const int ne##sfx = rlanei(rpn##sfx, CHUNK - 1) - S##sfx;                   \
    const float dvv##sfx = dinv[i0##sfx + min(lane, CHUNK - 1)];                \
    const int bvv##sfx = POOL ? batch[i0##sfx + min(lane, CHUNK - 1)] : 0;      \
    int node##sfx = 0;                                                          \
    int bnd##sfx = rlanei(rpn##sfx, 0) - S##sfx;                                \
    float acc##sfx = 0.0f;                                                      \
    float selfA##sfx = bfu2f(Ml[(size_t)i0##sfx * 64]);                         \
    float selfB##sfx = bfu2f(Ml[(size_t)(i0##sfx + 1) * 64]);                   \
    float selfC##sfx = bfu2f(Ml[(size_t)(i0##sfx + 2) * 64]);                   \
    int gcur##sfx = POOL ? rlanei(bvv##sfx, 0) : 0;                             \
    float rsum##sfx = 0.0f, rmax##sfx = 0.0f;                                   \
    int bidx##sfx = 0;                                                          \
    int colv0##sfx = 0, colv1##sfx = 0;                                         \
    unsigned ubuf##sfx[16];                                                     \
    int j##sfx = 0;

#define AGG_RING_INIT(sfx)                                                      \
    if (ne##sfx > 0) {                                                          \
        int a0_ = S##sfx + lane, a1_ = S##sfx + 64 + lane;                      \
        colv0##sfx = (a0_ < S##sfx + ne##sfx) ? cols[a0_] : 0;                  \
        colv1##sfx = (a1_ < S##sfx + ne##sfx) ? cols[a1_] : 0;                  \
        _Pragma("unroll")                                                       \
        for (int k_ = 0; k_ < 16; ++k_) {                                       \
            int e_ = min(k_, ne##sfx - 1);                                      \
            int cc_ = rlanei(colv0##sfx, e_);                                   \
            ubuf##sfx[k_] = Ml[(size_t)cc_ * 64];                               \
        }                                                                       \
    }

#define AGG_BLOCK16(sfx) {                                                      \
    _Pragma("unroll")                                                           \
    for (int k_ = 0; k_ < 16; ++k_) {                                           \
        const int jj_ = j##sfx + k_;                                            \
        if ((jj_ & 63) == 0 && jj_ != 0) {                                      \
            colv0##sfx = colv1##sfx;                                            \
            ++bidx##sfx;                                                        \
            int ad_ = S##sfx + (bidx##sfx + 1) * 64 + lane;                     \
            colv1##sfx = (ad_ < S##sfx + ne##sfx) ? cols[ad_] : 0;              \
        }                                                                       \
        while (jj_ == bnd##sfx) AGG_FINALIZE(sfx);                              \
        acc##sfx += __uint_as_float(ubuf##sfx[k_] << 16);                       \
        int ec_ = min(jj_ + 16, ne##sfx - 1);                                   \
        int src_ = ((ec_ >> 6) == bidx##sfx) ? colv0##sfx : colv1##sfx;         \
        int cc_ = rlanei(src_, ec_ & 63);                                       \
        ubuf##sfx[k_] = Ml[(size_t)cc_ * 64];                                   \
    }                                                                           \
    j##sfx += 16; }

#define AGG_TAIL(sfx) {                                                         \
    for (; j##sfx < ne##sfx; ++j##sfx) {                                        \
        while (j##sfx == bnd##sfx) AGG_FINALIZE(sfx);                           \
        acc##sfx += __uint_as_float(ubuf##sfx[j##sfx & 15] << 16);              \
    }                                                                           \
    while (node##sfx < CHUNK) AGG_FINALIZE(sfx);                                \
    AGG_FLUSH(sfx); }

template <int POOL>
__global__ __launch_bounds__(256, 4) void k_agg_seg(
        const bfu* __restrict__ M, const float* __restrict__ bias,
        const int* __restrict__ row_ptr, const int* __restrict__ cols,
        const float* __restrict__ dinv, const int* __restrict__ batch,
        bfu* __restrict__ out, float* __restrict__ psum,
        float* __restrict__ pmax) {
    const int lane = threadIdx.x & 63;
    const float b = bias[lane];
    const bfu* Ml = M + lane;   // per-lane base; row r at Ml[r*64]

    const int w = (blockIdx.x * 256 + threadIdx.x) >> 6;
    if (2 * w >= NCHUNK) return;     // NCHUNK even => chunk 2w+1 also valid

    AGG_INIT(A, 2 * w);
    AGG_RING_INIT(A);
    AGG_INIT(B, 2 * w + 1);
    AGG_RING_INIT(B);

    while (jA + 16 <= neA && jB + 16 <= neB) {
        AGG_BLOCK16(A);
        AGG_BLOCK16(B);
    }
    while (jA + 16 <= neA) AGG_BLOCK16(A);
    while (jB + 16 <= neB) AGG_BLOCK16(B);
    AGG_TAIL(A);
    AGG_TAIL(B);
}

// ---- assemble fused vector: [mean | max | relu(meta@Wm+bm) | emb | pad] ----
__global__ __launch_bounds__(256) void k_asm(
        const float* __restrict__ psum, const float* __restrict__ pmax,
        const int* __restrict__ gstart, const float* __restrict__ metadata,
        const int* __restrict__ species, const float* __restrict__ emb,
        const float* __restrict__ Wm, const float* __restrict__ bm,
        float* __restrict__ fused, int G) {
    const int lane = threadIdx.x & 63;
    int wv = (blockIdx.x * blockDim.x + threadIdx.x) >> 6;
    const int nw = (gridDim.x * blockDim.x) >> 6;
    const float bmr = bm[lane];
    float wmr[16];
#pragma unroll
    for (int k = 0; k < 16; ++k) wmr[k] = Wm[k * 64 + lane];
    for (int g = wv; g < G; g += nw) {
        float gc = (float)(gstart[g + 1] - gstart[g]);
        float mean = psum[(size_t)g * 64 + lane] / fmaxf(gc, 1.0f);
        float mx = pmax[(size_t)g * 64 + lane];
        float md = lane < 16 ? metadata[(size_t)g * 16 + lane] : 0.0f;
        float mval = bmr;
#pragma unroll
        for (int k = 0; k < 16; ++k) mval = fmaf(rlane(md, k), wmr[k], mval);
        mval = fmaxf(mval, 0.0f);
        const int sid = species[g];
        float* fr = fused + (size_t)g * 224;
        fr[lane] = mean;
        fr[64 + lane] = mx;
        fr[128 + lane] = mval;
        if (lane < 16) fr[192 + lane] = emb[(size_t)sid * 16 + lane];
        else if (lane < 32) fr[192 + lane] = 0.0f;
    }
}

// ---- MFMA predictor head ----
__global__ __launch_bounds__(256, 2) void k_pred_mfma(
        const float* __restrict__ fused, const float* __restrict__ Wp1,
        const float* __restrict__ bp1, const float* __restrict__ Wp2,
        const float* __restrict__ bp2, float* __restrict__ out, int G) {
    __shared__ __align__(16) short Whi[64 * 232];
    __shared__ __align__(16) short Wlo[64 * 232];
    const int t = threadIdx.x;
    for (int idx = t; idx < 64 * 232; idx += 256) {
        int n = idx / 232;
        int k = idx % 232;
        float w = (k < 208) ? Wp1[(size_t)k * 64 + n] : 0.0f;
        short hi = f2bf(w);
        Whi[n * 232 + k] = hi;
        Wlo[n * 232 + k] = f2bf(w - bf2f(hi));
    }
    __syncthreads();

    const int lane = t & 63;
    const int wave = t >> 6;
    const int m = lane & 15;
    const int q = lane >> 4;
    const int g0 = (blockIdx.x * 4 + wave) * 16;
    if (g0 >= G) return;

    const float* rowp = fused + (size_t)(g0 + m) * 224 + q * 8;

    f32x4 C[4];
#pragma unroll
    for (int nt = 0; nt < 4; ++nt) C[nt] = (f32x4){0.f, 0.f, 0.f, 0.f};

#pragma unroll
    for (int kt = 0; kt < 7; ++kt) {
        f32x4 a0 = *(const f32x4*)(rowp + kt * 32);
        f32x4 a1 = *(const f32x4*)(rowp + kt * 32 + 4);
        bf16x8 Ahi, Alo;
#pragma unroll
        for (int j = 0; j < 4; ++j) {
            short hi = f2bf(a0[j]);
            Ahi[j] = hi;
            Alo[j] = f2bf(a0[j] - bf2f(hi));
        }
#pragma unroll
        for (int j = 0; j < 4; ++j) {
            short hi = f2bf(a1[j]);
            Ahi[4 + j] = hi;
            Alo[4 + j] = f2bf(a1[j] - bf2f(hi));
        }
#pragma unroll
        for (int nt = 0; nt < 4; ++nt) {
            const int boff = (nt * 16 + m) * 232 + kt * 32 + q * 8;
            bf16x8 Bh = *(const bf16x8*)&Whi[boff];
            bf16x8 Bl = *(const bf16x8*)&Wlo[boff];
            C[nt] = __builtin_amdgcn_mfma_f32_16x16x32_bf16(Ahi, Bh, C[nt], 0, 0, 0);
            C[nt] = __builtin_amdgcn_mfma_f32_16x16x32_bf16(Ahi, Bl, C[nt], 0, 0, 0);
            C[nt] = __builtin_amdgcn_mfma_f32_16x16x32_bf16(Alo, Bh, C[nt], 0, 0, 0);
        }
    }

    float wp2r[4], bp1r[4];
#pragma unroll
    for (int nt = 0; nt < 4; ++nt) {
        wp2r[nt] = Wp2[nt * 16 + m];
        bp1r[nt] = bp1[nt * 16 + m];
    }
    const float bp2v = bp2[0];
    float s[4];
#pragma unroll
    for (int r = 0; r < 4; ++r) {
        float acc = 0.0f;
#pragma unroll
        for (int nt = 0; nt < 4; ++nt)
            acc += fmaxf(C[nt][r] + bp1r[nt], 0.0f) * wp2r[nt];
        s[r] = acc;
    }
#pragma unroll
    for (int off = 1; off < 16; off <<= 1) {
#pragma unroll
        for (int r = 0; r < 4; ++r) s[r] += __shfl_xor(s[r], off);
    }
    if (m == 0) {
#pragma unroll
        for (int r = 0; r < 4; ++r) out[g0 + q * 4 + r] = s[r] + bp2v;
    }
}

extern "C" void kernel_launch(void* const* d_in, const int* in_sizes, int n_in,
                              void* d_out, int out_size, void* d_ws, size_t ws_size,
                              hipStream_t stream) {
    const int N = N_NODES, E = N_EDGES, G = N_GRAPHS;

    const float* x        = (const float*)d_in[0];
    const float* metadata = (const float*)d_in[1];
    const int*   ei       = (const int*)d_in[2];
    const int*   batch    = (const int*)d_in[3];
    const int*   species  = (const int*)d_in[4];
    const float* W1 = (const float*)d_in[5];
    const float* b1 = (const float*)d_in[6];
    const float* W2 = (const float*)d_in[7];
    const float* b2 = (const float*)d_in[8];
    const float* W3 = (const float*)d_in[9];
    const float* b3 = (const float*)d_in[10];
    const float* Wm = (const float*)d_in[11];
    const float* bm = (const float*)d_in[12];
    const float* emb = (const float*)d_in[13];
    const float* Wp1 = (const float*)d_in[14];
    const float* bp1 = (const float*)d_in[15];
    const float* Wp2 = (const float*)d_in[16];
    const float* bp2 = (const float*)d_in[17];
    float* out = (float*)d_out;

    char* ws = (char*)d_ws;
    size_t off = 0;
    auto alloc = [&](size_t bytes) -> void* {
        void* p = ws + off;
        off = (off + bytes + 255) & ~(size_t)255;
        return p;
    };
    int*   row_ptr = (int*)alloc((size_t)(N + 1) * 4);
    float* dinv    = (float*)alloc((size_t)N * 4);
    int*   gstart  = (int*)alloc((size_t)(G + 1) * 4);
    int*   bkt     = (int*)alloc((size_t)NBKT * 4);
    int*   bbase   = (int*)alloc((size_t)(NBKT + 1) * 4);
    int*   bcur    = (int*)alloc((size_t)NBKT * 4);
    int*   colsS   = (int*)alloc((size_t)E * 4);
    float* psum    = (float*)alloc((size_t)G * 64 * 4);
    float* pmax    = (float*)alloc((size_t)G * 64 * 4);
    bfu*   Mb      = (bfu*)alloc((size_t)N * 64 * 2);    // bf16 GEMM output
    bfu*   hb      = (bfu*)alloc((size_t)N * 64 * 2);    // bf16 h' (agg output)
    float* fused   = (float*)alloc((size_t)G * 224 * 4);

    int2* tmp = (int2*)Mb;        // aliases Mb: dead until layer-1 GEMM writes it

    const int nbBin = (E + BIN_CHUNK - 1) / BIN_CHUNK;   // 391

    hipMemsetAsync(bkt, 0, (size_t)NBKT * 4, stream);
    hipMemsetAsync(psum, 0, (size_t)G * 64 * 4, stream);
    hipMemsetAsync(pmax, 0, (size_t)G * 64 * 4, stream);

    k_bcnt<<<nbBin, 256, 0, stream>>>(ei, bkt, E);
    k_bscan<<<1, 256, 0, stream>>>(bkt, bbase, bcur);
    k_bin<<<nbBin, 256, 0, stream>>>(ei, ei + E, bcur, tmp, E);
    k_csr<<<NBKT, 256, 0, stream>>>(tmp, bbase, row_ptr, dinv, colsS, N, E);
    k_gb<<<(N + 256) / 256 + 1, 256, 0, stream>>>(batch, gstart, N, G);

    const int nTiles = N / 16;          // 25000
    const int nbAgg = 1563;             // 6252 waves >= 6250 chunk-pairs
    // layer 1: M1 = (Dinv x) @ W1 (bf16) ; agg -> h1' bf16
    k_gemm_mfma<32, true, false><<<1563, 256, 0, stream>>>(x, W1, dinv, Mb, nTiles);
    k_agg_seg<0><<<nbAgg, 256, 0, stream>>>(Mb, b1, row_ptr, colsS, dinv, batch,
                                            hb, psum, pmax);
    // layer 2 (A bf16)
    k_gemm_mfma<64, false, true><<<1563, 256, 0, stream>>>(hb, W2, dinv, Mb, nTiles);
    k_agg_seg<0><<<nbAgg, 256, 0, stream>>>(Mb, b2, row_ptr, colsS, dinv, batch,
                                            hb, psum, pmax);
    // layer 3: GEMM (A bf16) then agg+pool (atomics into psum/pmax)
    k_gemm_mfma<64, false, true><<<1563, 256, 0, stream>>>(hb, W3, dinv, Mb, nTiles);
    k_agg_seg<1><<<nbAgg, 256, 0, stream>>>(Mb, b3, row_ptr, colsS, dinv, batch,
                                            hb, psum, pmax);

    k_asm<<<512, 256, 0, stream>>>(psum, pmax, gstart, metadata, species, emb, Wm, bm,
                                   fused, G);
    k_pred_mfma<<<(G / 16 + 3) / 4, 256, 0, stream>>>(fused, Wp1, bp1, Wp2, bp2, out, G);
}

// Round 7
// 478.783 us; speedup vs baseline: 2.7242x; 1.3197x over previous
//
#include <hip/hip_runtime.h>
#include <hip/hip_bf16.h>

#define N_NODES 400000
#define N_EDGES 1600000
#define N_GRAPHS 16384
#define CHUNK 50
#define NCHUNK (N_NODES / CHUNK)   // 8000 chunks == one full resident generation

#define BSHIFT 11
#define BKT_N (1 << BSHIFT)                               // 2048 rows per bucket
#define NBKT ((N_NODES + BKT_N - 1) >> BSHIFT)            // 196 row-buckets
#define BIN_CHUNK 4096

typedef __attribute__((ext_vector_type(8))) short bf16x8;
typedef __attribute__((ext_vector_type(4))) float f32x4;
typedef unsigned short bfu;

__device__ __forceinline__ float rlane(float x, int k) {
    return __int_as_float(__builtin_amdgcn_readlane(__float_as_int(x), k));
}
__device__ __forceinline__ int rlanei(int x, int k) {
    return __builtin_amdgcn_readlane(x, k);
}

__device__ __forceinline__ short f2bf(float x) {  // RNE float -> bf16 bits
    unsigned u = __float_as_uint(x);
    unsigned r = (u + 0x7fffu + ((u >> 16) & 1u)) >> 16;
    return (short)r;
}
__device__ __forceinline__ float bf2f(short b) {
    return __uint_as_float(((unsigned)(unsigned short)b) << 16);
}
__device__ __forceinline__ float bfu2f(bfu b) {
    return __uint_as_float(((unsigned)b) << 16);
}

// ---- bucket counts: LDS histogram, ~196 global atomics per block ----
__global__ __launch_bounds__(256) void k_bcnt(const int* __restrict__ rows,
                                              int* __restrict__ bkt, int E) {
    __shared__ int l[NBKT];
    const int t = threadIdx.x;
    for (int i = t; i < NBKT; i += 256) l[i] = 0;
    __syncthreads();
    const int e0 = blockIdx.x * BIN_CHUNK;
#pragma unroll
    for (int k = 0; k < 16; ++k) {
        int e = e0 + k * 256 + t;
        if (e < E) atomicAdd(&l[rows[e] >> BSHIFT], 1);
    }
    __syncthreads();
    for (int i = t; i < NBKT; i += 256)
        if (l[i]) atomicAdd(&bkt[i], l[i]);
}

// ---- single-block exclusive scan over NBKT bucket counts ----
__global__ void k_bscan(const int* __restrict__ bkt, int* __restrict__ bbase,
                        int* __restrict__ bcur) {
    __shared__ int s[256];
    const int t = threadIdx.x;
    int v = (t < NBKT) ? bkt[t] : 0;
    s[t] = v; __syncthreads();
    for (int off = 1; off < 256; off <<= 1) {
        int x = (t >= off) ? s[t - off] : 0;
        __syncthreads();
        s[t] += x;
        __syncthreads();
    }
    int excl = s[t] - v;
    if (t < NBKT) { bbase[t] = excl; bcur[t] = excl; }
    if (t == NBKT) bbase[NBKT] = excl;   // = E
}

// ---- bin edges by row-bucket (LDS-combined reservations) ----
__global__ __launch_bounds__(256) void k_bin(const int* __restrict__ rows,
                                             const int* __restrict__ cols,
                                             int* __restrict__ bcur,
                                             int2* __restrict__ tmp, int E) {
    __shared__ int lcnt[NBKT];
    __shared__ int lbase[NBKT];
    const int t = threadIdx.x;
    const int e0 = blockIdx.x * BIN_CHUNK;
    for (int i = t; i < NBKT; i += 256) lcnt[i] = 0;
    __syncthreads();
    int r[16];
#pragma unroll
    for (int k = 0; k < 16; ++k) {
        int e = e0 + k * 256 + t;
        r[k] = (e < E) ? rows[e] : -1;
        if (r[k] >= 0) atomicAdd(&lcnt[r[k] >> BSHIFT], 1);
    }
    __syncthreads();
    for (int i = t; i < NBKT; i += 256) lbase[i] = atomicAdd(&bcur[i], lcnt[i]);
    __syncthreads();
    for (int i = t; i < NBKT; i += 256) lcnt[i] = 0;
    __syncthreads();
#pragma unroll
    for (int k = 0; k < 16; ++k) {
        int e = e0 + k * 256 + t;
        if (r[k] >= 0) {
            int b = r[k] >> BSHIFT;
            int p = lbase[b] + atomicAdd(&lcnt[b], 1);
            tmp[p] = make_int2(r[k], cols[e]);
        }
    }
}

// ---- per-bucket CSR build: row_ptr + dinv + cols scatter, all block-local ----
__global__ __launch_bounds__(256) void k_csr(const int2* __restrict__ tmp,
                                             const int* __restrict__ bbase,
                                             int* __restrict__ row_ptr,
                                             float* __restrict__ dinv,
                                             int* __restrict__ colsOut,
                                             int N, int E) {
    __shared__ int lcnt[BKT_N];
    __shared__ int lofs[BKT_N];
    __shared__ int tsum[256];
    const int t = threadIdx.x;
    const int b = blockIdx.x;
    const int r0 = b << BSHIFT;
    const int S = bbase[b];
    const int T = bbase[b + 1];
    for (int i = t; i < BKT_N; i += 256) lcnt[i] = 0;
    __syncthreads();
    for (int e = S + t; e < T; e += 256) atomicAdd(&lcnt[tmp[e].x - r0], 1);
    __syncthreads();
    // block scan of 2048 counts: 8 sequential per thread + 256-thread scan
    const int base8 = t * 8;
    int vals[8];
    int run = 0;
#pragma unroll
    for (int k = 0; k < 8; ++k) { vals[k] = run; run += lcnt[base8 + k]; }
    tsum[t] = run;
    __syncthreads();
    for (int off = 1; off < 256; off <<= 1) {
        int x = (t >= off) ? tsum[t - off] : 0;
        __syncthreads();
        tsum[t] += x;
        __syncthreads();
    }
    const int texcl = tsum[t] - run;
#pragma unroll
    for (int k = 0; k < 8; ++k) lofs[base8 + k] = texcl + vals[k];
    __syncthreads();
    for (int i = t; i < BKT_N; i += 256) {
        int node = r0 + i;
        if (node < N) {
            row_ptr[node] = S + lofs[i];
            dinv[node] = rsqrtf((float)lcnt[i] + 1.0f);
        }
    }
    if (b == 0 && t == 0) row_ptr[N] = E;
    __syncthreads();
    // scatter cols; lofs doubles as LDS cursor
    for (int e = S + t; e < T; e += 256) {
        int2 rc = tmp[e];
        int pos = S + atomicAdd(&lofs[rc.x - r0], 1);
        colsOut[pos] = rc.y;
    }
}

// ---- gstart from sorted batch via boundary detection (no atomics) ----
__global__ void k_gb(const int* __restrict__ batch, int* __restrict__ gstart,
                     int N, int G) {
    int i = blockIdx.x * blockDim.x + threadIdx.x;
    if (i <= N) {
        int b = (i < N) ? batch[i] : G;
        int prev = (i == 0) ? -1 : batch[i - 1];
        for (int g = prev + 1; g <= b; ++g) gstart[g] = i;
    }
}

// ---- MFMA GEMM (grid-stride over 16-node tiles).
// ABF16=0: A fp32, split hi/lo (3 MFMAs per nt,kt), optional dinv prescale.
// ABF16=1: A already bf16 (2 MFMAs per nt,kt). Output always bf16.
template <int IN_D, bool PRESCALE, bool ABF16>
__global__ __launch_bounds__(256, 4) void k_gemm_mfma(
        const void* __restrict__ in_, const float* __restrict__ W,
        const float* __restrict__ dinv, bfu* __restrict__ out, int nTiles) {
    constexpr int KT = IN_D / 32;
    const int lane = threadIdx.x & 63;
    const int m = lane & 15;
    const int q = lane >> 4;

    bf16x8 Bhi[4][KT], Blo[4][KT];
#pragma unroll
    for (int nt = 0; nt < 4; ++nt) {
#pragma unroll
        for (int kt = 0; kt < KT; ++kt) {
#pragma unroll
            for (int j = 0; j < 8; ++j) {
                int k = kt * 32 + q * 8 + j;
                float w = W[k * 64 + nt * 16 + m];
                short hi = f2bf(w);
                Bhi[nt][kt][j] = hi;
                Blo[nt][kt][j] = f2bf(w - bf2f(hi));
            }
        }
    }

    const int wv = (blockIdx.x * 256 + threadIdx.x) >> 6;
    const int nwv = (gridDim.x * 256) >> 6;

    for (int tile = wv; tile < nTiles; tile += nwv) {
        const int node0 = tile * 16;
        f32x4 C[4];
#pragma unroll
        for (int nt = 0; nt < 4; ++nt) C[nt] = (f32x4){0.f, 0.f, 0.f, 0.f};

        if (ABF16) {
            const bfu* rowb = (const bfu*)in_ + (size_t)(node0 + m) * IN_D + q * 8;
            bf16x8 A[KT];
#pragma unroll
            for (int kt = 0; kt < KT; ++kt) A[kt] = *(const bf16x8*)(rowb + kt * 32);
#pragma unroll
            for (int nt = 0; nt < 4; ++nt) {
#pragma unroll
                for (int kt = 0; kt < KT; ++kt) {
                    C[nt] = __builtin_amdgcn_mfma_f32_16x16x32_bf16(A[kt], Bhi[nt][kt], C[nt], 0, 0, 0);
                    C[nt] = __builtin_amdgcn_mfma_f32_16x16x32_bf16(A[kt], Blo[nt][kt], C[nt], 0, 0, 0);
                }
            }
        } else {
            const float dv = PRESCALE ? dinv[node0 + m] : 1.0f;
            const float* rowp = (const float*)in_ + (size_t)(node0 + m) * IN_D + q * 8;
            bf16x8 Ahi[KT], Alo[KT];
#pragma unroll
            for (int kt = 0; kt < KT; ++kt) {
                f32x4 a0 = *(const f32x4*)(rowp + kt * 32);
                f32x4 a1 = *(const f32x4*)(rowp + kt * 32 + 4);
#pragma unroll
                for (int j = 0; j < 4; ++j) {
                    float xx = PRESCALE ? dv * a0[j] : a0[j];
                    short hi = f2bf(xx);
                    Ahi[kt][j] = hi;
                    Alo[kt][j] = f2bf(xx - bf2f(hi));
                }
#pragma unroll
                for (int j = 0; j < 4; ++j) {
                    float xx = PRESCALE ? dv * a1[j] : a1[j];
                    short hi = f2bf(xx);
                    Ahi[kt][4 + j] = hi;
                    Alo[kt][4 + j] = f2bf(xx - bf2f(hi));
                }
            }
#pragma unroll
            for (int nt = 0; nt < 4; ++nt) {
#pragma unroll
                for (int kt = 0; kt < KT; ++kt) {
                    C[nt] = __builtin_amdgcn_mfma_f32_16x16x32_bf16(Ahi[kt], Bhi[nt][kt], C[nt], 0, 0, 0);
                    C[nt] = __builtin_amdgcn_mfma_f32_16x16x32_bf16(Ahi[kt], Blo[nt][kt], C[nt], 0, 0, 0);
                    C[nt] = __builtin_amdgcn_mfma_f32_16x16x32_bf16(Alo[kt], Bhi[nt][kt], C[nt], 0, 0, 0);
                }
            }
        }

        bfu* op = out + (size_t)node0 * 64;
#pragma unroll
        for (int nt = 0; nt < 4; ++nt) {
#pragma unroll
            for (int r = 0; r < 4; ++r) {
                op[(size_t)(q * 4 + r) * 64 + nt * 16 + m] = (bfu)f2bf(C[nt][r]);
            }
        }
    }
}

// ==== segmented-stream aggregation over bf16 M rows ====
// R7 = exact R1 body (16-deep VGPR ring; col window in VGPRs + per-edge
// readlane [R3: no per-edge memory loads]; ring depth 16 [R4: 32 spills];
// static schedule [R5: atomic counter poison]; single stream [R2/R6: pairing
// costs more VALU than it saves]) with CHUNK=50: N = 50*8000 => exactly 8000
// chunks = one full resident generation (8000 <= 8192 wave slots), removing
// R1's 1.53-generation tail (occupancy 59% -> ~90%+).
// POOL=0: out[i] = bf16( dinv[i] * relu(dinv[i]*(M_i + sum_j M_j) + b) )
// POOL=1: h3 = relu(...) pooled per graph-run -> atomics into psum/pmax.
template <int POOL>
__global__ __launch_bounds__(256, 8) void k_agg_seg(
        const bfu* __restrict__ M, const float* __restrict__ bias,
        const int* __restrict__ row_ptr, const int* __restrict__ cols,
        const float* __restrict__ dinv, const int* __restrict__ batch,
        bfu* __restrict__ out, float* __restrict__ psum,
        float* __restrict__ pmax) {
    const int lane = threadIdx.x & 63;
    int wid = (blockIdx.x * blockDim.x + threadIdx.x) >> 6;
    wid = __builtin_amdgcn_readfirstlane(wid);
    const int nw = (gridDim.x * blockDim.x) >> 6;
    const float b = bias[lane];
    const bfu* Ml = M + lane;   // per-lane base; row r at Ml[r*64]

    for (int c = wid; c < NCHUNK; c += nw) {
        const int i0 = c * CHUNK;
        const int rpn = row_ptr[i0 + min(lane, CHUNK - 1) + 1];
        const int S = row_ptr[i0];
        const int ne = rlanei(rpn, CHUNK - 1) - S;
        const float dvv = dinv[i0 + min(lane, CHUNK - 1)];
        const int bvv = POOL ? batch[i0 + min(lane, CHUNK - 1)] : 0;

        int node = 0;
        int bnd = rlanei(rpn, 0) - S;
        float acc = 0.0f;
        float selfA = bfu2f(Ml[(size_t)i0 * 64]);
        float selfB = bfu2f(Ml[(size_t)(i0 + 1) * 64]);
        float selfC = bfu2f(Ml[(size_t)(i0 + 2) * 64]);
        int gcur = POOL ? rlanei(bvv, 0) : 0;
        float rsum = 0.0f, rmax = 0.0f;

        auto flush = [&]() {
            if (POOL) {
                atomicAdd(&psum[(size_t)gcur * 64 + lane], rsum);
                atomicMax((int*)&pmax[(size_t)gcur * 64 + lane], __float_as_int(rmax));
            }
        };
        auto finalize = [&]() {
            const float d = rlane(dvv, node);
            const float h = fmaxf(fmaf(d, selfA + acc, b), 0.0f);
            if (POOL) {
                const int g = rlanei(bvv, node);
                if (g != gcur) { flush(); gcur = g; rsum = 0.0f; rmax = 0.0f; }
                rsum += h;
                rmax = fmaxf(rmax, h);
            } else {
                out[(size_t)(i0 + node) * 64 + lane] = (bfu)f2bf(d * h);
            }
            acc = 0.0f;
            selfA = selfB;
            selfB = selfC;
            if (node + 3 < CHUNK) selfC = bfu2f(Ml[(size_t)(i0 + node + 3) * 64]);
            ++node;
            if (node < CHUNK) bnd = rlanei(rpn, node) - S;
        };

        if (ne > 0) {
            int bidx = 0;
            int a0 = S + lane, a1 = S + 64 + lane;
            int colv0 = (a0 < S + ne) ? cols[a0] : 0;
            int colv1 = (a1 < S + ne) ? cols[a1] : 0;
            unsigned ubuf[16];
#pragma unroll
            for (int k = 0; k < 16; ++k) {
                int e = min(k, ne - 1);
                int cc = rlanei(colv0, e);
                ubuf[k] = Ml[(size_t)cc * 64];
            }

            int j = 0;
            while (j + 16 <= ne) {
#pragma unroll
                for (int k = 0; k < 16; ++k) {
                    const int jj = j + k;
                    if ((jj & 63) == 0 && jj != 0) {
                        colv0 = colv1;
                        ++bidx;
                        int ad = S + (bidx + 1) * 64 + lane;
                        colv1 = (ad < S + ne) ? cols[ad] : 0;
                    }
                    while (jj == bnd) finalize();
                    acc += __uint_as_float(ubuf[k] << 16);
                    int ec = min(jj + 16, ne - 1);
                    int src = ((ec >> 6) == bidx) ? colv0 : colv1;
                    int cc = rlanei(src, ec & 63);
                    ubuf[k] = Ml[(size_t)cc * 64];
                }
                j += 16;
            }
            for (; j < ne; ++j) {
                while (j == bnd) finalize();
                acc += __uint_as_float(ubuf[j & 15] << 16);
            }
        }
        while (node < CHUNK) finalize();
        flush();
    }
}

// ---- assemble fused vector: [mean | max | relu(meta@Wm+bm) | emb | pad] ----
__global__ __launch_bounds__(256) void k_asm(
        const float* __restrict__ psum, const float* __restrict__ pmax,
        const int* __restrict__ gstart, const float* __restrict__ metadata,
        const int* __restrict__ species, const float* __restrict__ emb,
        const float* __restrict__ Wm, const float* __restrict__ bm,
        float* __restrict__ fused, int G) {
    const int lane = threadIdx.x & 63;
    int wv = (blockIdx.x * blockDim.x + threadIdx.x) >> 6;
    const int nw = (gridDim.x * blockDim.x) >> 6;
    const float bmr = bm[lane];
    float wmr[16];
#pragma unroll
    for (int k = 0; k < 16; ++k) wmr[k] = Wm[k * 64 + lane];
    for (int g = wv; g < G; g += nw) {
        float gc = (float)(gstart[g + 1] - gstart[g]);
        float mean = psum[(size_t)g * 64 + lane] / fmaxf(gc, 1.0f);
        float mx = pmax[(size_t)g * 64 + lane];
        float md = lane < 16 ? metadata[(size_t)g * 16 + lane] : 0.0f;
        float mval = bmr;
#pragma unroll
        for (int k = 0; k < 16; ++k) mval = fmaf(rlane(md, k), wmr[k], mval);
        mval = fmaxf(mval, 0.0f);
        const int sid = species[g];
        float* fr = fused + (size_t)g * 224;
        fr[lane] = mean;
        fr[64 + lane] = mx;
        fr[128 + lane] = mval;
        if (lane < 16) fr[192 + lane] = emb[(size_t)sid * 16 + lane];
        else if (lane < 32) fr[192 + lane] = 0.0f;
    }
}

// ---- MFMA predictor head ----
__global__ __launch_bounds__(256, 2) void k_pred_mfma(
        const float* __restrict__ fused, const float* __restrict__ Wp1,
        const float* __restrict__ bp1, const float* __restrict__ Wp2,
        const float* __restrict__ bp2, float* __restrict__ out, int G) {
    __shared__ __align__(16) short Whi[64 * 232];
    __shared__ __align__(16) short Wlo[64 * 232];
    const int t = threadIdx.x;
    for (int idx = t; idx < 64 * 232; idx += 256) {
        int n = idx / 232;
        int k = idx % 232;
        float w = (k < 208) ? Wp1[(size_t)k * 64 + n] : 0.0f;
        short hi = f2bf(w);
        Whi[n * 232 + k] = hi;
        Wlo[n * 232 + k] = f2bf(w - bf2f(hi));
    }
    __syncthreads();

    const int lane = t & 63;
    const int wave = t >> 6;
    const int m = lane & 15;
    const int q = lane >> 4;
    const int g0 = (blockIdx.x * 4 + wave) * 16;
    if (g0 >= G) return;

    const float* rowp = fused + (size_t)(g0 + m) * 224 + q * 8;

    f32x4 C[4];
#pragma unroll
    for (int nt = 0; nt < 4; ++nt) C[nt] = (f32x4){0.f, 0.f, 0.f, 0.f};

#pragma unroll
    for (int kt = 0; kt < 7; ++kt) {
        f32x4 a0 = *(const f32x4*)(rowp + kt * 32);
        f32x4 a1 = *(const f32x4*)(rowp + kt * 32 + 4);
        bf16x8 Ahi, Alo;
#pragma unroll
        for (int j = 0; j < 4; ++j) {
            short hi = f2bf(a0[j]);
            Ahi[j] = hi;
            Alo[j] = f2bf(a0[j] - bf2f(hi));
        }
#pragma unroll
        for (int j = 0; j < 4; ++j) {
            short hi = f2bf(a1[j]);
            Ahi[4 + j] = hi;
            Alo[4 + j] = f2bf(a1[j] - bf2f(hi));
        }
#pragma unroll
        for (int nt = 0; nt < 4; ++nt) {
            const int boff = (nt * 16 + m) * 232 + kt * 32 + q * 8;
            bf16x8 Bh = *(const bf16x8*)&Whi[boff];
            bf16x8 Bl = *(const bf16x8*)&Wlo[boff];
            C[nt] = __builtin_amdgcn_mfma_f32_16x16x32_bf16(Ahi, Bh, C[nt], 0, 0, 0);
            C[nt] = __builtin_amdgcn_mfma_f32_16x16x32_bf16(Ahi, Bl, C[nt], 0, 0, 0);
            C[nt] = __builtin_amdgcn_mfma_f32_16x16x32_bf16(Alo, Bh, C[nt], 0, 0, 0);
        }
    }

    float wp2r[4], bp1r[4];
#pragma unroll
    for (int nt = 0; nt < 4; ++nt) {
        wp2r[nt] = Wp2[nt * 16 + m];
        bp1r[nt] = bp1[nt * 16 + m];
    }
    const float bp2v = bp2[0];
    float s[4];
#pragma unroll
    for (int r = 0; r < 4; ++r) {
        float acc = 0.0f;
#pragma unroll
        for (int nt = 0; nt < 4; ++nt)
            acc += fmaxf(C[nt][r] + bp1r[nt], 0.0f) * wp2r[nt];
        s[r] = acc;
    }
#pragma unroll
    for (int off = 1; off < 16; off <<= 1) {
#pragma unroll
        for (int r = 0; r < 4; ++r) s[r] += __shfl_xor(s[r], off);
    }
    if (m == 0) {
#pragma unroll
        for (int r = 0; r < 4; ++r) out[g0 + q * 4 + r] = s[r] + bp2v;
    }
}

extern "C" void kernel_launch(void* const* d_in, const int* in_sizes, int n_in,
                              void* d_out, int out_size, void* d_ws, size_t ws_size,
                              hipStream_t stream) {
    const int N = N_NODES, E = N_EDGES, G = N_GRAPHS;

    const float* x        = (const float*)d_in[0];
    const float* metadata = (const float*)d_in[1];
    const int*   ei       = (const int*)d_in[2];
    const int*   batch    = (const int*)d_in[3];
    const int*   species  = (const int*)d_in[4];
    const float* W1 = (const float*)d_in[5];
    const float* b1 = (const float*)d_in[6];
    const float* W2 = (const float*)d_in[7];
    const float* b2 = (const float*)d_in[8];
    const float* W3 = (const float*)d_in[9];
    const float* b3 = (const float*)d_in[10];
    const float* Wm = (const float*)d_in[11];
    const float* bm = (const float*)d_in[12];
    const float* emb = (const float*)d_in[13];
    const float* Wp1 = (const float*)d_in[14];
    const float* bp1 = (const float*)d_in[15];
    const float* Wp2 = (const float*)d_in[16];
    const float* bp2 = (const float*)d_in[17];
    float* out = (float*)d_out;

    char* ws = (char*)d_ws;
    size_t off = 0;
    auto alloc = [&](size_t bytes) -> void* {
        void* p = ws + off;
        off = (off + bytes + 255) & ~(size_t)255;
        return p;
    };
    int*   row_ptr = (int*)alloc((size_t)(N + 1) * 4);
    float* dinv    = (float*)alloc((size_t)N * 4);
    int*   gstart  = (int*)alloc((size_t)(G + 1) * 4);
    int*   bkt     = (int*)alloc((size_t)NBKT * 4);
    int*   bbase   = (int*)alloc((size_t)(NBKT + 1) * 4);
    int*   bcur    = (int*)alloc((size_t)NBKT * 4);
    int*   colsS   = (int*)alloc((size_t)E * 4);
    float* psum    = (float*)alloc((size_t)G * 64 * 4);
    float* pmax    = (float*)alloc((size_t)G * 64 * 4);
    bfu*   Mb      = (bfu*)alloc((size_t)N * 64 * 2);    // bf16 GEMM output
    bfu*   hb      = (bfu*)alloc((size_t)N * 64 * 2);    // bf16 h' (agg output)
    float* fused   = (float*)alloc((size_t)G * 224 * 4);

    int2* tmp = (int2*)Mb;        // aliases Mb: dead until layer-1 GEMM writes it

    const int nbBin = (E + BIN_CHUNK - 1) / BIN_CHUNK;   // 391

    hipMemsetAsync(bkt, 0, (size_t)NBKT * 4, stream);
    hipMemsetAsync(psum, 0, (size_t)G * 64 * 4, stream);
    hipMemsetAsync(pmax, 0, (size_t)G * 64 * 4, stream);

    k_bcnt<<<nbBin, 256, 0, stream>>>(ei, bkt, E);
    k_bscan<<<1, 256, 0, stream>>>(bkt, bbase, bcur);
    k_bin<<<nbBin, 256, 0, stream>>>(ei, ei + E, bcur, tmp, E);
    k_csr<<<NBKT, 256, 0, stream>>>(tmp, bbase, row_ptr, dinv, colsS, N, E);
    k_gb<<<(N + 256) / 256 + 1, 256, 0, stream>>>(batch, gstart, N, G);

    const int nTiles = N / 16;          // 25000
    const int nbAgg = NCHUNK / 4;       // 2000 blocks = 8000 waves = NCHUNK
    // layer 1: M1 = (Dinv x) @ W1 (bf16) ; agg -> h1' bf16
    k_gemm_mfma<32, true, false><<<1563, 256, 0, stream>>>(x, W1, dinv, Mb, nTiles);
    k_agg_seg<0><<<nbAgg, 256, 0, stream>>>(Mb, b1, row_ptr, colsS, dinv, batch,
                                            hb, psum, pmax);
    // layer 2 (A bf16)
    k_gemm_mfma<64, false, true><<<1563, 256, 0, stream>>>(hb, W2, dinv, Mb, nTiles);
    k_agg_seg<0><<<nbAgg, 256, 0, stream>>>(Mb, b2, row_ptr, colsS, dinv, batch,
                                            hb, psum, pmax);
    // layer 3: GEMM (A bf16) then agg+pool (atomics into psum/pmax)
    k_gemm_mfma<64, false, true><<<1563, 256, 0, stream>>>(hb, W3, dinv, Mb, nTiles);
    k_agg_seg<1><<<nbAgg, 256, 0, stream>>>(Mb, b3, row_ptr, colsS, dinv, batch,
                                            hb, psum, pmax);

    k_asm<<<512, 256, 0, stream>>>(psum, pmax, gstart, metadata, species, emb, Wm, bm,
                                   fused, G);
    k_pred_mfma<<<(G / 16 + 3) / 4, 256, 0, stream>>>(fused, Wp1, bp1, Wp2, bp2, out, G);
}

// Round 8
// 477.929 us; speedup vs baseline: 2.7291x; 1.0018x over previous
//
#include <hip/hip_runtime.h>
#include <hip/hip_bf16.h>

#define N_NODES 400000
#define N_EDGES 1600000
#define N_GRAPHS 16384
#define CHUNK 50
#define NCHUNK (N_NODES / CHUNK)   // 8000 chunks == one full resident generation

#define BSHIFT 9
#define BKT_N (1 << BSHIFT)                               // 512 rows per bucket
#define NBKT ((N_NODES + BKT_N - 1) >> BSHIFT)            // 782 row-buckets
#define BIN_CHUNK 4096
#define NBBIN ((N_EDGES + BIN_CHUNK - 1) / BIN_CHUNK)     // 391

typedef __attribute__((ext_vector_type(8))) short bf16x8;
typedef __attribute__((ext_vector_type(4))) float f32x4;
typedef unsigned short bfu;

__device__ __forceinline__ float rlane(float x, int k) {
    return __int_as_float(__builtin_amdgcn_readlane(__float_as_int(x), k));
}
__device__ __forceinline__ int rlanei(int x, int k) {
    return __builtin_amdgcn_readlane(x, k);
}

__device__ __forceinline__ short f2bf(float x) {  // RNE float -> bf16 bits
    unsigned u = __float_as_uint(x);
    unsigned r = (u + 0x7fffu + ((u >> 16) & 1u)) >> 16;
    return (short)r;
}
__device__ __forceinline__ float bf2f(short b) {
    return __uint_as_float(((unsigned)(unsigned short)b) << 16);
}
__device__ __forceinline__ float bfu2f(bfu b) {
    return __uint_as_float(((unsigned)b) << 16);
}

// ---- fused: bucket counts (blocks < NBBIN) + gstart boundary detect (all) ----
__global__ __launch_bounds__(256) void k_bcnt_gb(const int* __restrict__ rows,
                                                 int* __restrict__ bkt,
                                                 const int* __restrict__ batch,
                                                 int* __restrict__ gstart,
                                                 int N, int G, int E) {
    __shared__ int l[NBKT];
    const int t = threadIdx.x;
    const int b = blockIdx.x;
    // gstart part: every thread covers one i in [0, N]
    int i = b * 256 + t;
    if (i <= N) {
        int bb = (i < N) ? batch[i] : G;
        int prev = (i == 0) ? -1 : batch[i - 1];
        for (int g = prev + 1; g <= bb; ++g) gstart[g] = i;
    }
    // histogram part: first NBBIN blocks
    if (b < NBBIN) {
        for (int k = t; k < NBKT; k += 256) l[k] = 0;
        __syncthreads();
        const int e0 = b * BIN_CHUNK;
#pragma unroll
        for (int k = 0; k < 16; ++k) {
            int e = e0 + k * 256 + t;
            if (e < E) atomicAdd(&l[rows[e] >> BSHIFT], 1);
        }
        __syncthreads();
        for (int k = t; k < NBKT; k += 256)
            if (l[k]) atomicAdd(&bkt[k], l[k]);
    }
}

// ---- bin edges by row-bucket; per-block recomputed scan of bkt[] +
// zero-based global cursors (bcur0 pre-zeroed) replace the bscan kernel ----
__global__ __launch_bounds__(256) void k_bin(const int* __restrict__ rows,
                                             const int* __restrict__ cols,
                                             const int* __restrict__ bkt,
                                             int* __restrict__ bcur0,
                                             int2* __restrict__ tmp, int E) {
    __shared__ int lcnt[NBKT];
    __shared__ int gbase[NBKT];
    __shared__ int lbase[NBKT];
    __shared__ int tsum[256];
    const int t = threadIdx.x;
    // 1. local histogram of this edge chunk
    for (int i = t; i < NBKT; i += 256) lcnt[i] = 0;
    __syncthreads();
    const int e0 = blockIdx.x * BIN_CHUNK;
    int r[16];
#pragma unroll
    for (int k = 0; k < 16; ++k) {
        int e = e0 + k * 256 + t;
        r[k] = (e < E) ? rows[e] : -1;
        if (r[k] >= 0) atomicAdd(&lcnt[r[k] >> BSHIFT], 1);
    }
    // 2. block-local exclusive scan of global bkt -> gbase (4 entries/thread)
    const int base4 = t * 4;
    int v[4];
    int run = 0;
#pragma unroll
    for (int k = 0; k < 4; ++k) {
        int idx = base4 + k;
        int x = (idx < NBKT) ? bkt[idx] : 0;
        v[k] = run;
        run += x;
    }
    tsum[t] = run;
    __syncthreads();
    for (int off = 1; off < 256; off <<= 1) {
        int x = (t >= off) ? tsum[t - off] : 0;
        __syncthreads();
        tsum[t] += x;
        __syncthreads();
    }
    const int texcl = tsum[t] - run;
#pragma unroll
    for (int k = 0; k < 4; ++k) {
        int idx = base4 + k;
        if (idx < NBKT) gbase[idx] = texcl + v[k];
    }
    __syncthreads();
    // 3. reserve per-bucket ranges (zero-based cursor + recomputed base)
    for (int i = t; i < NBKT; i += 256) {
        int c = lcnt[i];
        lbase[i] = c ? (gbase[i] + atomicAdd(&bcur0[i], c)) : 0;
    }
    __syncthreads();
    for (int i = t; i < NBKT; i += 256) lcnt[i] = 0;
    __syncthreads();
#pragma unroll
    for (int k = 0; k < 16; ++k) {
        if (r[k] >= 0) {
            int b = r[k] >> BSHIFT;
            int p = lbase[b] + atomicAdd(&lcnt[b], 1);
            tmp[p] = make_int2(r[k], cols[e0 + k * 256 + t]);
        }
    }
}

// ---- per-bucket CSR build; block computes its own base via reduction ----
__global__ __launch_bounds__(256) void k_csr(const int2* __restrict__ tmp,
                                             const int* __restrict__ bkt,
                                             int* __restrict__ row_ptr,
                                             float* __restrict__ dinv,
                                             int* __restrict__ colsOut,
                                             int N, int E) {
    __shared__ int lcnt[BKT_N];
    __shared__ int lofs[BKT_N];
    __shared__ int tsum[256];
    const int t = threadIdx.x;
    const int b = blockIdx.x;
    const int r0 = b << BSHIFT;
    // S = sum bkt[0..b) via block reduction
    int part = 0;
    for (int i = t; i < b; i += 256) part += bkt[i];
    tsum[t] = part;
    __syncthreads();
    for (int off = 128; off > 0; off >>= 1) {
        if (t < off) tsum[t] += tsum[t + off];
        __syncthreads();
    }
    const int S = tsum[0];
    const int T = S + bkt[b];
    __syncthreads();
    for (int i = t; i < BKT_N; i += 256) lcnt[i] = 0;
    __syncthreads();
    for (int e = S + t; e < T; e += 256) atomicAdd(&lcnt[tmp[e].x - r0], 1);
    __syncthreads();
    // block scan of 512 counts: 2 sequential per thread + 256-thread scan
    const int base2 = t * 2;
    int vals[2];
    int run = 0;
#pragma unroll
    for (int k = 0; k < 2; ++k) { vals[k] = run; run += lcnt[base2 + k]; }
    tsum[t] = run;
    __syncthreads();
    for (int off = 1; off < 256; off <<= 1) {
        int x = (t >= off) ? tsum[t - off] : 0;
        __syncthreads();
        tsum[t] += x;
        __syncthreads();
    }
    const int texcl = tsum[t] - run;
#pragma unroll
    for (int k = 0; k < 2; ++k) lofs[base2 + k] = texcl + vals[k];
    __syncthreads();
    for (int i = t; i < BKT_N; i += 256) {
        int node = r0 + i;
        if (node < N) {
            row_ptr[node] = S + lofs[i];
            dinv[node] = rsqrtf((float)lcnt[i] + 1.0f);
        }
    }
    if (b == 0 && t == 0) row_ptr[N] = E;
    __syncthreads();
    // scatter cols; lofs doubles as LDS cursor
    for (int e = S + t; e < T; e += 256) {
        int2 rc = tmp[e];
        int pos = S + atomicAdd(&lofs[rc.x - r0], 1);
        colsOut[pos] = rc.y;
    }
}

// ---- MFMA GEMM (grid-stride over 16-node tiles).
// ABF16=0: A fp32, split hi/lo (3 MFMAs per nt,kt), optional dinv prescale.
// ABF16=1: A already bf16 (2 MFMAs per nt,kt). Output always bf16.
template <int IN_D, bool PRESCALE, bool ABF16>
__global__ __launch_bounds__(256, 4) void k_gemm_mfma(
        const void* __restrict__ in_, const float* __restrict__ W,
        const float* __restrict__ dinv, bfu* __restrict__ out, int nTiles) {
    constexpr int KT = IN_D / 32;
    const int lane = threadIdx.x & 63;
    const int m = lane & 15;
    const int q = lane >> 4;

    bf16x8 Bhi[4][KT], Blo[4][KT];
#pragma unroll
    for (int nt = 0; nt < 4; ++nt) {
#pragma unroll
        for (int kt = 0; kt < KT; ++kt) {
#pragma unroll
            for (int j = 0; j < 8; ++j) {
                int k = kt * 32 + q * 8 + j;
                float w = W[k * 64 + nt * 16 + m];
                short hi = f2bf(w);
                Bhi[nt][kt][j] = hi;
                Blo[nt][kt][j] = f2bf(w - bf2f(hi));
            }
        }
    }

    const int wv = (blockIdx.x * 256 + threadIdx.x) >> 6;
    const int nwv = (gridDim.x * 256) >> 6;

    for (int tile = wv; tile < nTiles; tile += nwv) {
        const int node0 = tile * 16;
        f32x4 C[4];
#pragma unroll
        for (int nt = 0; nt < 4; ++nt) C[nt] = (f32x4){0.f, 0.f, 0.f, 0.f};

        if (ABF16) {
            const bfu* rowb = (const bfu*)in_ + (size_t)(node0 + m) * IN_D + q * 8;
            bf16x8 A[KT];
#pragma unroll
            for (int kt = 0; kt < KT; ++kt) A[kt] = *(const bf16x8*)(rowb + kt * 32);
#pragma unroll
            for (int nt = 0; nt < 4; ++nt) {
#pragma unroll
                for (int kt = 0; kt < KT; ++kt) {
                    C[nt] = __builtin_amdgcn_mfma_f32_16x16x32_bf16(A[kt], Bhi[nt][kt], C[nt], 0, 0, 0);
                    C[nt] = __builtin_amdgcn_mfma_f32_16x16x32_bf16(A[kt], Blo[nt][kt], C[nt], 0, 0, 0);
                }
            }
        } else {
            const float dv = PRESCALE ? dinv[node0 + m] : 1.0f;
            const float* rowp = (const float*)in_ + (size_t)(node0 + m) * IN_D + q * 8;
            bf16x8 Ahi[KT], Alo[KT];
#pragma unroll
            for (int kt = 0; kt < KT; ++kt) {
                f32x4 a0 = *(const f32x4*)(rowp + kt * 32);
                f32x4 a1 = *(const f32x4*)(rowp + kt * 32 + 4);
#pragma unroll
                for (int j = 0; j < 4; ++j) {
                    float xx = PRESCALE ? dv * a0[j] : a0[j];
                    short hi = f2bf(xx);
                    Ahi[kt][j] = hi;
                    Alo[kt][j] = f2bf(xx - bf2f(hi));
                }
#pragma unroll
                for (int j = 0; j < 4; ++j) {
                    float xx = PRESCALE ? dv * a1[j] : a1[j];
                    short hi = f2bf(xx);
                    Ahi[kt][4 + j] = hi;
                    Alo[kt][4 + j] = f2bf(xx - bf2f(hi));
                }
            }
#pragma unroll
            for (int nt = 0; nt < 4; ++nt) {
#pragma unroll
                for (int kt = 0; kt < KT; ++kt) {
                    C[nt] = __builtin_amdgcn_mfma_f32_16x16x32_bf16(Ahi[kt], Bhi[nt][kt], C[nt], 0, 0, 0);
                    C[nt] = __builtin_amdgcn_mfma_f32_16x16x32_bf16(Ahi[kt], Blo[nt][kt], C[nt], 0, 0, 0);
                    C[nt] = __builtin_amdgcn_mfma_f32_16x16x32_bf16(Alo[kt], Bhi[nt][kt], C[nt], 0, 0, 0);
                }
            }
        }

        bfu* op = out + (size_t)node0 * 64;
#pragma unroll
        for (int nt = 0; nt < 4; ++nt) {
#pragma unroll
            for (int r = 0; r < 4; ++r) {
                op[(size_t)(q * 4 + r) * 64 + nt * 16 + m] = (bfu)f2bf(C[nt][r]);
            }
        }
    }
}

// ==== segmented-stream aggregation over bf16 M rows ====
// Converged body (R7): 16-deep VGPR ring; col window in VGPRs + per-edge
// readlane [R3: no per-edge memory loads]; ring depth 16 [R4: 32 spills];
// static schedule [R5: atomic counter poison]; single stream [R2/R6];
// CHUNK=50 -> 8000 chunks = one resident generation.
// POOL=0: out[i] = bf16( dinv[i] * relu(dinv[i]*(M_i + sum_j M_j) + b) )
// POOL=1: h3 = relu(...) pooled per graph-run -> atomics into psum/pmax.
template <int POOL>
__global__ __launch_bounds__(256, 8) void k_agg_seg(
        const bfu* __restrict__ M, const float* __restrict__ bias,
        const int* __restrict__ row_ptr, const int* __restrict__ cols,
        const float* __restrict__ dinv, const int* __restrict__ batch,
        bfu* __restrict__ out, float* __restrict__ psum,
        float* __restrict__ pmax) {
    const int lane = threadIdx.x & 63;
    int wid = (blockIdx.x * blockDim.x + threadIdx.x) >> 6;
    wid = __builtin_amdgcn_readfirstlane(wid);
    const int nw = (gridDim.x * blockDim.x) >> 6;
    const float b = bias[lane];
    const bfu* Ml = M + lane;   // per-lane base; row r at Ml[r*64]

    for (int c = wid; c < NCHUNK; c += nw) {
        const int i0 = c * CHUNK;
        const int rpn = row_ptr[i0 + min(lane, CHUNK - 1) + 1];
        const int S = row_ptr[i0];
        const int ne = rlanei(rpn, CHUNK - 1) - S;
        const float dvv = dinv[i0 + min(lane, CHUNK - 1)];
        const int bvv = POOL ? batch[i0 + min(lane, CHUNK - 1)] : 0;

        int node = 0;
        int bnd = rlanei(rpn, 0) - S;
        float acc = 0.0f;
        float selfA = bfu2f(Ml[(size_t)i0 * 64]);
        float selfB = bfu2f(Ml[(size_t)(i0 + 1) * 64]);
        float selfC = bfu2f(Ml[(size_t)(i0 + 2) * 64]);
        int gcur = POOL ? rlanei(bvv, 0) : 0;
        float rsum = 0.0f, rmax = 0.0f;

        auto flush = [&]() {
            if (POOL) {
                atomicAdd(&psum[(size_t)gcur * 64 + lane], rsum);
                atomicMax((int*)&pmax[(size_t)gcur * 64 + lane], __float_as_int(rmax));
            }
        };
        auto finalize = [&]() {
            const float d = rlane(dvv, node);
            const float h = fmaxf(fmaf(d, selfA + acc, b), 0.0f);
            if (POOL) {
                const int g = rlanei(bvv, node);
                if (g != gcur) { flush(); gcur = g; rsum = 0.0f; rmax = 0.0f; }
                rsum += h;
                rmax = fmaxf(rmax, h);
            } else {
                out[(size_t)(i0 + node) * 64 + lane] = (bfu)f2bf(d * h);
            }
            acc = 0.0f;
            selfA = selfB;
            selfB = selfC;
            if (node + 3 < CHUNK) selfC = bfu2f(Ml[(size_t)(i0 + node + 3) * 64]);
            ++node;
            if (node < CHUNK) bnd = rlanei(rpn, node) - S;
        };

        if (ne > 0) {
            int bidx = 0;
            int a0 = S + lane, a1 = S + 64 + lane;
            int colv0 = (a0 < S + ne) ? cols[a0] : 0;
            int colv1 = (a1 < S + ne) ? cols[a1] : 0;
            unsigned ubuf[16];
#pragma unroll
            for (int k = 0; k < 16; ++k) {
                int e = min(k, ne - 1);
                int cc = rlanei(colv0, e);
                ubuf[k] = Ml[(size_t)cc * 64];
            }

            int j = 0;
            while (j + 16 <= ne) {
#pragma unroll
                for (int k = 0; k < 16; ++k) {
                    const int jj = j + k;
                    if ((jj & 63) == 0 && jj != 0) {
                        colv0 = colv1;
                        ++bidx;
                        int ad = S + (bidx + 1) * 64 + lane;
                        colv1 = (ad < S + ne) ? cols[ad] : 0;
                    }
                    while (jj == bnd) finalize();
                    acc += __uint_as_float(ubuf[k] << 16);
                    int ec = min(jj + 16, ne - 1);
                    int src = ((ec >> 6) == bidx) ? colv0 : colv1;
                    int cc = rlanei(src, ec & 63);
                    ubuf[k] = Ml[(size_t)cc * 64];
                }
                j += 16;
            }
            for (; j < ne; ++j) {
                while (j == bnd) finalize();
                acc += __uint_as_float(ubuf[j & 15] << 16);
            }
        }
        while (node < CHUNK) finalize();
        flush();
    }
}

// ---- assemble fused vector: [mean | max | relu(meta@Wm+bm) | emb | pad] ----
__global__ __launch_bounds__(256) void k_asm(
        const float* __restrict__ psum, const float* __restrict__ pmax,
        const int* __restrict__ gstart, const float* __restrict__ metadata,
        const int* __restrict__ species, const float* __restrict__ emb,
        const float* __restrict__ Wm, const float* __restrict__ bm,
        float* __restrict__ fused, int G) {
    const int lane = threadIdx.x & 63;
    int wv = (blockIdx.x * blockDim.x + threadIdx.x) >> 6;
    const int nw = (gridDim.x * blockDim.x) >> 6;
    const float bmr = bm[lane];
    float wmr[16];
#pragma unroll
    for (int k = 0; k < 16; ++k) wmr[k] = Wm[k * 64 + lane];
    for (int g = wv; g < G; g += nw) {
        float gc = (float)(gstart[g + 1] - gstart[g]);
        float mean = psum[(size_t)g * 64 + lane] / fmaxf(gc, 1.0f);
        float mx = pmax[(size_t)g * 64 + lane];
        float md = lane < 16 ? metadata[(size_t)g * 16 + lane] : 0.0f;
        float mval = bmr;
#pragma unroll
        for (int k = 0; k < 16; ++k) mval = fmaf(rlane(md, k), wmr[k], mval);
        mval = fmaxf(mval, 0.0f);
        const int sid = species[g];
        float* fr = fused + (size_t)g * 224;
        fr[lane] = mean;
        fr[64 + lane] = mx;
        fr[128 + lane] = mval;
        if (lane < 16) fr[192 + lane] = emb[(size_t)sid * 16 + lane];
        else if (lane < 32) fr[192 + lane] = 0.0f;
    }
}

// ---- MFMA predictor head ----
__global__ __launch_bounds__(256, 2) void k_pred_mfma(
        const float* __restrict__ fused, const float* __restrict__ Wp1,
        const float* __restrict__ bp1, const float* __restrict__ Wp2,
        const float* __restrict__ bp2, float* __restrict__ out, int G) {
    __shared__ __align__(16) short Whi[64 * 232];
    __shared__ __align__(16) short Wlo[64 * 232];
    const int t = threadIdx.x;
    for (int idx = t; idx < 64 * 232; idx += 256) {
        int n = idx / 232;
        int k = idx % 232;
        float w = (k < 208) ? Wp1[(size_t)k * 64 + n] : 0.0f;
        short hi = f2bf(w);
        Whi[n * 232 + k] = hi;
        Wlo[n * 232 + k] = f2bf(w - bf2f(hi));
    }
    __syncthreads();

    const int lane = t & 63;
    const int wave = t >> 6;
    const int m = lane & 15;
    const int q = lane >> 4;
    const int g0 = (blockIdx.x * 4 + wave) * 16;
    if (g0 >= G) return;

    const float* rowp = fused + (size_t)(g0 + m) * 224 + q * 8;

    f32x4 C[4];
#pragma unroll
    for (int nt = 0; nt < 4; ++nt) C[nt] = (f32x4){0.f, 0.f, 0.f, 0.f};

#pragma unroll
    for (int kt = 0; kt < 7; ++kt) {
        f32x4 a0 = *(const f32x4*)(rowp + kt * 32);
        f32x4 a1 = *(const f32x4*)(rowp + kt * 32 + 4);
        bf16x8 Ahi, Alo;
#pragma unroll
        for (int j = 0; j < 4; ++j) {
            short hi = f2bf(a0[j]);
            Ahi[j] = hi;
            Alo[j] = f2bf(a0[j] - bf2f(hi));
        }
#pragma unroll
        for (int j = 0; j < 4; ++j) {
            short hi = f2bf(a1[j]);
            Ahi[4 + j] = hi;
            Alo[4 + j] = f2bf(a1[j] - bf2f(hi));
        }
#pragma unroll
        for (int nt = 0; nt < 4; ++nt) {
            const int boff = (nt * 16 + m) * 232 + kt * 32 + q * 8;
            bf16x8 Bh = *(const bf16x8*)&Whi[boff];
            bf16x8 Bl = *(const bf16x8*)&Wlo[boff];
            C[nt] = __builtin_amdgcn_mfma_f32_16x16x32_bf16(Ahi, Bh, C[nt], 0, 0, 0);
            C[nt] = __builtin_amdgcn_mfma_f32_16x16x32_bf16(Ahi, Bl, C[nt], 0, 0, 0);
            C[nt] = __builtin_amdgcn_mfma_f32_16x16x32_bf16(Alo, Bh, C[nt], 0, 0, 0);
        }
    }

    float wp2r[4], bp1r[4];
#pragma unroll
    for (int nt = 0; nt < 4; ++nt) {
        wp2r[nt] = Wp2[nt * 16 + m];
        bp1r[nt] = bp1[nt * 16 + m];
    }
    const float bp2v = bp2[0];
    float s[4];
#pragma unroll
    for (int r = 0; r < 4; ++r) {
        float acc = 0.0f;
#pragma unroll
        for (int nt = 0; nt < 4; ++nt)
            acc += fmaxf(C[nt][r] + bp1r[nt], 0.0f) * wp2r[nt];
        s[r] = acc;
    }
#pragma unroll
    for (int off = 1; off < 16; off <<= 1) {
#pragma unroll
        for (int r = 0; r < 4; ++r) s[r] += __shfl_xor(s[r], off);
    }
    if (m == 0) {
#pragma unroll
        for (int r = 0; r < 4; ++r) out[g0 + q * 4 + r] = s[r] + bp2v;
    }
}

extern "C" void kernel_launch(void* const* d_in, const int* in_sizes, int n_in,
                              void* d_out, int out_size, void* d_ws, size_t ws_size,
                              hipStream_t stream) {
    const int N = N_NODES, E = N_EDGES, G = N_GRAPHS;

    const float* x        = (const float*)d_in[0];
    const float* metadata = (const float*)d_in[1];
    const int*   ei       = (const int*)d_in[2];
    const int*   batch    = (const int*)d_in[3];
    const int*   species  = (const int*)d_in[4];
    const float* W1 = (const float*)d_in[5];
    const float* b1 = (const float*)d_in[6];
    const float* W2 = (const float*)d_in[7];
    const float* b2 = (const float*)d_in[8];
    const float* W3 = (const float*)d_in[9];
    const float* b3 = (const float*)d_in[10];
    const float* Wm = (const float*)d_in[11];
    const float* bm = (const float*)d_in[12];
    const float* emb = (const float*)d_in[13];
    const float* Wp1 = (const float*)d_in[14];
    const float* bp1 = (const float*)d_in[15];
    const float* Wp2 = (const float*)d_in[16];
    const float* bp2 = (const float*)d_in[17];
    float* out = (float*)d_out;

    char* ws = (char*)d_ws;
    size_t off = 0;
    auto alloc = [&](size_t bytes) -> void* {
        void* p = ws + off;
        off = (off + bytes + 255) & ~(size_t)255;
        return p;
    };
    int*   row_ptr = (int*)alloc((size_t)(N + 1) * 4);
    float* dinv    = (float*)alloc((size_t)N * 4);
    int*   gstart  = (int*)alloc((size_t)(G + 1) * 4);
    // ---- contiguous zero region: bkt | bcur | psum | pmax (single memset) ----
    size_t z0 = off;
    int*   bkt     = (int*)alloc((size_t)NBKT * 4);
    int*   bcur    = (int*)alloc((size_t)NBKT * 4);
    float* psum    = (float*)alloc((size_t)G * 64 * 4);
    float* pmax    = (float*)alloc((size_t)G * 64 * 4);
    size_t zlen = off - z0;
    // -------------------------------------------------------------------------
    int*   colsS   = (int*)alloc((size_t)E * 4);
    bfu*   Mb      = (bfu*)alloc((size_t)N * 64 * 2);    // bf16 GEMM output
    bfu*   hb      = (bfu*)alloc((size_t)N * 64 * 2);    // bf16 h' (agg output)
    float* fused   = (float*)alloc((size_t)G * 224 * 4);

    int2* tmp = (int2*)Mb;        // aliases Mb: dead until layer-1 GEMM writes it

    hipMemsetAsync(ws + z0, 0, zlen, stream);

    const int nbGb = (N + 256) / 256 + 1;                // 1563 >= NBBIN(391)
    k_bcnt_gb<<<nbGb, 256, 0, stream>>>(ei, bkt, batch, gstart, N, G, E);
    k_bin<<<NBBIN, 256, 0, stream>>>(ei, ei + E, bkt, bcur, tmp, E);
    k_csr<<<NBKT, 256, 0, stream>>>(tmp, bkt, row_ptr, dinv, colsS, N, E);

    const int nTiles = N / 16;          // 25000
    const int nbAgg = NCHUNK / 4;       // 2000 blocks = 8000 waves = NCHUNK
    // layer 1: M1 = (Dinv x) @ W1 (bf16) ; agg -> h1' bf16
    k_gemm_mfma<32, true, false><<<1563, 256, 0, stream>>>(x, W1, dinv, Mb, nTiles);
    k_agg_seg<0><<<nbAgg, 256, 0, stream>>>(Mb, b1, row_ptr, colsS, dinv, batch,
                                            hb, psum, pmax);
    // layer 2 (A bf16)
    k_gemm_mfma<64, false, true><<<1563, 256, 0, stream>>>(hb, W2, dinv, Mb, nTiles);
    k_agg_seg<0><<<nbAgg, 256, 0, stream>>>(Mb, b2, row_ptr, colsS, dinv, batch,
                                            hb, psum, pmax);
    // layer 3: GEMM (A bf16) then agg+pool (atomics into psum/pmax)
    k_gemm_mfma<64, false, true><<<1563, 256, 0, stream>>>(hb, W3, dinv, Mb, nTiles);
    k_agg_seg<1><<<nbAgg, 256, 0, stream>>>(Mb, b3, row_ptr, colsS, dinv, batch,
                                            hb, psum, pmax);

    k_asm<<<512, 256, 0, stream>>>(psum, pmax, gstart, metadata, species, emb, Wm, bm,
                                   fused, G);
    k_pred_mfma<<<(G / 16 + 3) / 4, 256, 0, stream>>>(fused, Wp1, bp1, Wp2, bp2, out, G);
}